// Round 11
// baseline (185.684 us; speedup 1.0000x reference)
//
#include <hip/hip_runtime.h>

// KPConv simple block: grid + block-union MFMA KPConv + BN + LeakyReLU
// B=8, N=4096 -> M=32768; C_IN=64, C_OUT=128, K=15 kernel pts.
//
// Exact simplification: influence w = max(1 - d/0.04, 0) with ||kp||<=0.042
// => candidates with ||rel|| >= 0.082 contribute 0 to every kernel point.
//
// R23 = R20 (proven 170.0 us) + wave-COHERENT chunk skip in k2a.
// R22's per-lane early-outs regressed (+4 us): ~40% random liveness =>
// every wave mixed => pays both paths. Fix: skip at (q,chunk) granularity.
//  - search builds 16-bit per-query in-ball mask (same hit set as min),
//    packed into Pu.w: (mask<<12)|pos  (pos<4096).
//  - stage-1: wave-OR of the chunk's 32 masks -> chmask; (q,chunk) with
//    bit clear => ALL influences exactly zero => coherent zero-fill.
//  - R22's divergent early-outs dropped; k2b = R20 256-block (proven).

#define NB     8
#define NPTS   4096
#define M_TOT  32768
#define CIN    64
#define COUT   128
#define NKP    15
#define NCELL  1728            // 12^3
#define UCAP   400             // union cap (mean ~70)
#define R2EFF  (0.082f * 0.082f)
#define KP_INV 25.0f           // 1 / KP_EXTENT(0.04)
#define NEG_SLOPE 0.2f
#define KCP    960             // kc' = k*64+c, k-major, k=15 dropped
#define WFROW  1920            // wf row stride bytes (960 bf16)
#define SP     40              // S/FT row stride (shorts), 80B

typedef float f32x4_t __attribute__((ext_vector_type(4)));
typedef short bf16x8_t __attribute__((ext_vector_type(8)));

__device__ __forceinline__ unsigned short f2bf(float f) {
  union { float f; unsigned u; } v; v.f = f;
  unsigned r = v.u + 0x7FFF + ((v.u >> 16) & 1);   // RNE
  return (unsigned short)(r >> 16);
}
// half-up rounding: same 0.5 ulp max error as RNE, 2 VALU ops
__device__ __forceinline__ unsigned short f2bf_fast(float f) {
  union { float f; unsigned u; } v; v.f = f;
  return (unsigned short)((v.u + 0x8000u) >> 16);
}
__device__ __forceinline__ int cell_of(float x, float y, float z) {
  int cx = (int)(x * 12.f); cx = cx > 11 ? 11 : cx;
  int cy = (int)(y * 12.f); cy = cy > 11 ? 11 : cy;
  int cz = (int)(z * 12.f); cz = cz > 11 ? 11 : cz;
  return (cz * 12 + cy) * 12 + cx;
}
// async global->LDS, 16B per lane; LDS dest = uniform base + lane*16
__device__ __forceinline__ void gld_lds16(const unsigned short* g, void* l) {
  __builtin_amdgcn_global_load_lds(
      (const __attribute__((address_space(1))) unsigned int*)g,
      (__attribute__((address_space(3))) unsigned int*)l, 16, 0, 0);
}

// ---------------------------------------------------------------------------
// K0a: per-cell histogram
// ---------------------------------------------------------------------------
__global__ __launch_bounds__(256) void k0a_hist(
    const float* __restrict__ xyz, int* __restrict__ cellcnt)
{
  const int pt = blockIdx.x * 256 + threadIdx.x;
  const float x = xyz[pt * 3], y = xyz[pt * 3 + 1], z = xyz[pt * 3 + 2];
  const int b = pt >> 12;
  atomicAdd(&cellcnt[b * NCELL + cell_of(x, y, z)], 1);
}

// ---------------------------------------------------------------------------
// K0b: blocks 0..7 = per-batch exclusive scan; blocks 8..39 = W -> Wt
// Wt[d][k*64+c] bf16, k-major, k=15 dropped.
// ---------------------------------------------------------------------------
__global__ __launch_bounds__(256) void k0b_scan_kW(
    const int* __restrict__ cellcnt, int* __restrict__ cellstart,
    const float* __restrict__ W, unsigned short* __restrict__ Wt)
{
  if (blockIdx.x >= 8) {
    const int idx = (blockIdx.x - 8) * 256 + threadIdx.x;  // 8192
    const int c = idx & 63, d = idx >> 6;                  // d 0..127
    #pragma unroll
    for (int k = 0; k < NKP; k++)
      Wt[(size_t)d * KCP + k * 64 + c] =
          f2bf(W[(size_t)k * (CIN * COUT) + c * COUT + d]);
    return;
  }
  __shared__ int ps[256];
  const int b = blockIdx.x, t = threadIdx.x;
  int local[7], s = 0;
  #pragma unroll
  for (int i = 0; i < 7; i++) {
    const int cid = t * 7 + i;
    const int c = (cid < NCELL) ? cellcnt[b * NCELL + cid] : 0;
    local[i] = c; s += c;
  }
  ps[t] = s; __syncthreads();
  for (int off = 1; off < 256; off <<= 1) {
    int v = (t >= off) ? ps[t - off] : 0;
    __syncthreads();
    ps[t] += v;
    __syncthreads();
  }
  int run = ps[t] - s;
  #pragma unroll
  for (int i = 0; i < 7; i++) {
    const int cid = t * 7 + i;
    if (cid < NCELL) { cellstart[b * 1729 + cid] = run; run += local[i]; }
  }
  if (t == 255) cellstart[b * 1729 + NCELL] = ps[255];
}

// ---------------------------------------------------------------------------
// K0c: counting-sort scatter -> qorder + sorted xyz + sorted bf16 feats
// ---------------------------------------------------------------------------
__global__ __launch_bounds__(256) void k0c_scatter(
    const float* __restrict__ xyz, const float* __restrict__ feats,
    const int* __restrict__ cellstart, int* __restrict__ cellfill,
    int* __restrict__ qorder, float4* __restrict__ xyzs,
    unsigned short* __restrict__ fsorted)
{
  const int pt = blockIdx.x * 256 + threadIdx.x;
  const float x = xyz[pt * 3], y = xyz[pt * 3 + 1], z = xyz[pt * 3 + 2];
  const int b = pt >> 12;
  const int cid = cell_of(x, y, z);
  const int slot = atomicAdd(&cellfill[b * NCELL + cid], 1);
  const int pos = b * NPTS + cellstart[b * 1729 + cid] + slot;
  qorder[pos] = pt;
  xyzs[pos] = make_float4(x, y, z, 0.f);
  const float* src = &feats[(size_t)pt * CIN];
  uint4* dst = (uint4*)&fsorted[(size_t)pos * CIN];
  #pragma unroll
  for (int g = 0; g < 8; g++) {
    float4 a = *(const float4*)(src + g * 8);
    float4 c = *(const float4*)(src + g * 8 + 4);
    union { unsigned short s[8]; uint4 v; } u;
    u.s[0] = f2bf(a.x); u.s[1] = f2bf(a.y); u.s[2] = f2bf(a.z); u.s[3] = f2bf(a.w);
    u.s[4] = f2bf(c.x); u.s[5] = f2bf(c.y); u.s[6] = f2bf(c.z); u.s[7] = f2bf(c.w);
    dst[g] = u.v;
  }
}

// ---------------------------------------------------------------------------
// K2a: search + stage-1, result -> wfg[32768][960] bf16 (coalesced dump)
// ---------------------------------------------------------------------------
__global__ __launch_bounds__(256, 5) void k2a_conv(
    const float4* __restrict__ xyzs, const unsigned short* __restrict__ fsorted,
    const float* __restrict__ kpts, const int* __restrict__ cellstart,
    unsigned short* __restrict__ wfg)
{
  // phase-aliased LDS (32000 B):
  //   [0..6400)       Pu[400] float4   (.w packs (qmask<<12)|pos)
  //   [6400..14592)   cpos[4096] ushort
  //   [6400..26880)   S[128][40] short
  //   [26880..32000)  FT[64][40] short
  //   [0..30720)      wf 16 x 1920 B (XOR-swizzled; writeback+dump)
  __shared__ char smraw[32000] __attribute__((aligned(16)));
  float4*         Pu   = (float4*)smraw;
  unsigned short* cpos = (unsigned short*)(smraw + 6400);
  short (*S)[SP]       = (short(*)[SP])(smraw + 6400);
  short (*FT)[SP]      = (short(*)[SP])(smraw + 26880);

  __shared__ float4 qd[16];
  __shared__ float  kp[NKP][4];   // (-2kx, -2ky, -2kz, |kp|^2)
  __shared__ int    Tsh;
  __shared__ int    ucnt;

  const int tid = threadIdx.x;
  const int w   = tid >> 6;
  const int L   = tid & 63;
  // XCD batch swizzle: XCD x (= bid&7) owns tiles [x*256, x*256+256) ==
  // batch x exactly -> per-XCD gather set (fsorted 512KB + xyzs 64KB) L2-hot.
  const int tile = ((blockIdx.x & 7) << 8) | (blockIdx.x >> 3);
  const int m0  = tile * 16;
  const int b   = blockIdx.x & 7;

  if (tid >= 64 && tid < 64 + NKP) {
    const int k = tid - 64;
    const float kx = kpts[k * 3], ky = kpts[k * 3 + 1], kz = kpts[k * 3 + 2];
    kp[k][0] = -2.f * kx; kp[k][1] = -2.f * ky; kp[k][2] = -2.f * kz;
    kp[k][3] = kx * kx + ky * ky + kz * kz;
  }

  // ---- wave-0 prologue: bbox -> row ranges -> pfx (shfl scan) -> cpos ----
  if (tid < 64) {
    int cxm = 12, cym = 12, czm = 12, cxM = -1, cyM = -1, czM = -1;
    if (tid < 16) {
      const float4 Q = xyzs[m0 + tid];
      qd[tid] = Q;
      int a = (int)(Q.x * 12.f); a = a > 11 ? 11 : a;
      int c = (int)(Q.y * 12.f); c = c > 11 ? 11 : c;
      int d = (int)(Q.z * 12.f); d = d > 11 ? 11 : d;
      cxm = cxM = a; cym = cyM = c; czm = czM = d;
    }
    #pragma unroll
    for (int off = 8; off >= 1; off >>= 1) {
      int v;
      v = __shfl_xor(cxm, off); cxm = v < cxm ? v : cxm;
      v = __shfl_xor(cxM, off); cxM = v > cxM ? v : cxM;
      v = __shfl_xor(cym, off); cym = v < cym ? v : cym;
      v = __shfl_xor(cyM, off); cyM = v > cyM ? v : cyM;
      v = __shfl_xor(czm, off); czm = v < czm ? v : czm;
      v = __shfl_xor(czM, off); czM = v > czM ? v : czM;
    }
    cxm = __shfl(cxm, 0); cxM = __shfl(cxM, 0);
    cym = __shfl(cym, 0); cyM = __shfl(cyM, 0);
    czm = __shfl(czm, 0); czM = __shfl(czM, 0);

    const int x0 = cxm > 0 ? cxm - 1 : 0, x1 = cxM < 11 ? cxM + 1 : 11;
    const int y0 = cym > 0 ? cym - 1 : 0, y1 = cyM < 11 ? cyM + 1 : 11;
    const int z0 = czm > 0 ? czm - 1 : 0, z1 = czM < 11 ? czM + 1 : 11;
    const int yspan = y1 - y0 + 1;
    int nr = yspan * (z1 - z0 + 1);
    nr = nr > 64 ? 64 : nr;

    int rs = 0, len = 0;
    if (tid < nr) {
      const int zz = z0 + tid / yspan, yy = y0 + tid % yspan;
      const int base = b * 1729 + (zz * 12 + yy) * 12;
      rs  = cellstart[base + x0];
      len = cellstart[base + x1 + 1] - rs;
    }
    int incl = len;
    #pragma unroll
    for (int off = 1; off < 64; off <<= 1) {
      const int v = __shfl_up(incl, off);
      if (tid >= off) incl += v;
    }
    const int excl = incl - len;
    for (int i = 0; i < len; i++) cpos[excl + i] = (unsigned short)(rs + i);
    if (tid == 63) Tsh = incl;
    if (tid == 62) ucnt = 0;
  }
  __syncthreads();
  const int T = Tsh;

  // ---- union search: per-query in-ball mask (same hit set as min) ----
  for (int tb = 0; tb < T; tb += 256) {
    const int t = tb + tid;
    if (t < T) {
      const int pos = (int)cpos[t];
      const float4 P = xyzs[b * NPTS + pos];
      unsigned m = 0;
      #pragma unroll
      for (int i = 0; i < 16; i++) {
        const float4 Q = qd[i];
        const float dx = P.x - Q.x, dy = P.y - Q.y, dz = P.z - Q.z;
        const float d2 = dx * dx + dy * dy + dz * dz;
        m |= (d2 <= R2EFF) ? (1u << i) : 0u;
      }
      if (m) {
        const int slot = atomicAdd(&ucnt, 1);
        if (slot < UCAP)
          Pu[slot] = make_float4(
              P.x, P.y, P.z,
              __int_as_float((int)((m << 12) | (unsigned)pos)));
      }
    }
  }
  __syncthreads();
  int U = ucnt; U = U > UCAP ? UCAP : U;

  // ---- stage-1: chunked MFMA over the union, two 8-query half-passes ----
  const int ln = L & 15;
  const int kh = L >> 4;
  const int qh = tid >> 5;      // 0..7 local query of this half
  const int nn = tid & 31;      // chunk column

  f32x4_t acc[16];
  #pragma unroll
  for (int mt = 0; mt < 16; mt++) acc[mt] = (f32x4_t){0.f, 0.f, 0.f, 0.f};

  for (int ub = 0; ub < U; ub += 32) {
    // FT[c][i]: sorted bf16 rows (L2-hot, spatially local)
    {
      const int c  = tid & 63;
      const int i0 = tid >> 6;
      #pragma unroll
      for (int ii = 0; ii < 8; ii++) {
        const int i = ii * 4 + i0;
        const int u = ub + i;
        short v = 0;
        if (u < U) {
          const int pos = __float_as_int(Pu[u].w) & 0xFFF;
          v = (short)fsorted[(size_t)(b * NPTS + pos) * CIN + c];
        }
        FT[c][i] = v;
      }
    }

    // chunk q-liveness: OR of the 32 candidate masks (wave-coherent)
    unsigned chmask;
    {
      const int u = ub + (tid & 31);
      unsigned cm = 0;
      if (u < U) cm = ((unsigned)__float_as_int(Pu[u].w)) >> 12;
      #pragma unroll
      for (int off = 1; off < 64; off <<= 1)
        cm |= (unsigned)__shfl_xor((int)cm, off);
      chmask = cm;
    }

    bf16x8_t bb;   // FT fragment, reused by both halves
    #pragma unroll
    for (int half = 0; half < 2; half++) {
      // S fill: (q,chunk) with mask bit clear => all influences exactly 0
      // (d >= 0.082-0.042 = 0.04 => w = 0) -> coherent zero-fill.
      {
        const int q = half * 8 + qh;
        const int u = ub + nn;
        if (((chmask >> q) & 1) && u < U) {
          const float4 P = Pu[u];
          const float4 Q = qd[q];
          const float rx = P.x - Q.x, ry = P.y - Q.y, rz = P.z - Q.z;
          const float rr = rx * rx + ry * ry + rz * rz;
          #pragma unroll
          for (int k = 0; k < NKP; k++) {
            float d2 = fmaf(kp[k][0], rx,
                       fmaf(kp[k][1], ry,
                       fmaf(kp[k][2], rz, rr + kp[k][3])));
            d2 = fmaxf(d2, 0.f);
            const float wv =
                fmaxf(fmaf(-KP_INV, __builtin_amdgcn_sqrtf(d2), 1.f), 0.f);
            S[qh * 16 + k][nn] = (short)f2bf_fast(wv);
          }
          S[qh * 16 + 15][nn] = 0;
        } else {
          #pragma unroll
          for (int k = 0; k < 16; k++) S[qh * 16 + k][nn] = 0;
        }
      }
      __syncthreads();
      if (half == 0) bb = *(const bf16x8_t*)&FT[w * 16 + ln][kh * 8];
      #pragma unroll
      for (int mt = 0; mt < 8; mt++) {
        bf16x8_t aa = *(const bf16x8_t*)&S[mt * 16 + ln][kh * 8];
        acc[half * 8 + mt] =
            __builtin_amdgcn_mfma_f32_16x16x32_bf16(aa, bb, acc[half * 8 + mt],
                                                    0, 0, 0);
      }
      __syncthreads();
    }
  }

  // ---- writeback: acc -> LDS wf (swizzled; S/FT/Pu dead) ----
  {
    const int c = w * 16 + ln;
    #pragma unroll
    for (int mt = 0; mt < 16; mt++) {
      #pragma unroll
      for (int j = 0; j < 4; j++) {
        const int k = kh * 4 + j;
        if (k < 15) {
          const int byteo = (mt * WFROW + ((k * 64 + c) << 1)) ^ ((mt & 7) << 4);
          *(unsigned short*)(smraw + byteo) = f2bf_fast(acc[mt][j]);
        }
      }
    }
  }
  __syncthreads();

  // ---- dump: LDS wf -> wfg linear, coalesced uint4 (30720 B/block) ----
  for (int i = tid; i < 16 * 120; i += 256) {
    const int r  = i / 120;
    const int ch = i - r * 120;
    const uint4 v =
        *(const uint4*)(smraw + ((r * WFROW + ch * 16) ^ ((r & 7) << 4)));
    *(uint4*)(wfg + (size_t)(m0 + r) * KCP + ch * 8) = v;
  }
}

// ---------------------------------------------------------------------------
// K2b: tiled GEMM out[32768][128] = wfg[32768][960] @ Wt[128][960]^T
// 256 blocks x 128x128 tile, BK=64, 4 waves 2x2 (64x64 each), glds staging,
// double-buffered prefetch. kc accumulation order == R14/R18 (bitwise-same).
// (R20 version, proven.)
// ---------------------------------------------------------------------------
__global__ __launch_bounds__(256, 2) void k2b_gemm(
    const unsigned short* __restrict__ wfg,
    const unsigned short* __restrict__ Wt,
    const int* __restrict__ qorder, float* __restrict__ out,
    float* __restrict__ psum, float* __restrict__ psumsq)
{
  __shared__ char smA[2][16384] __attribute__((aligned(16)));
  __shared__ char smB[2][16384] __attribute__((aligned(16)));
  __shared__ int  qm[128];

  const int tid = threadIdx.x;
  const int w   = tid >> 6;
  const int L   = tid & 63;
  const int m0  = blockIdx.x * 128;

  if (tid < 128) qm[tid] = qorder[m0 + tid];

  const int c16 = L & 7;

#define STAGE_TILES(buf, ks)                                                 \
  {                                                                          \
    _Pragma("unroll")                                                        \
    for (int i = 0; i < 4; i++) {                                            \
      const int row = (w * 4 + i) * 8 + (L >> 3);                            \
      const int sc  = (c16 ^ (row & 7)) << 3;   /* shorts */                 \
      gld_lds16(wfg + (size_t)(m0 + row) * KCP + (ks) * 64 + sc,             \
                (char*)smA[buf] + (w * 4 + i) * 1024);                       \
      gld_lds16(Wt + (size_t)row * KCP + (ks) * 64 + sc,                     \
                (char*)smB[buf] + (w * 4 + i) * 1024);                       \
    }                                                                        \
  }

  STAGE_TILES(0, 0)
  __syncthreads();

  const int wr = w >> 1, wc = w & 1;
  const int ln = L & 15, kh = L >> 4;

  f32x4_t acc[4][4];
  #pragma unroll
  for (int mt = 0; mt < 4; mt++)
    #pragma unroll
    for (int nt = 0; nt < 4; nt++)
      acc[mt][nt] = (f32x4_t){0.f, 0.f, 0.f, 0.f};

  int cur = 0;
  for (int ks = 0; ks < 15; ks++) {
    if (ks < 14) STAGE_TILES(cur ^ 1, ks + 1)   // prefetch under compute

    const char* cA = smA[cur];
    const char* cB = smB[cur];
    #pragma unroll
    for (int ks2 = 0; ks2 < 2; ks2++) {
      bf16x8_t a[4], bfr[4];
      #pragma unroll
      for (int mt = 0; mt < 4; mt++) {
        const int row  = wr * 64 + mt * 16 + ln;
        const int phys = ((ks2 * 4 + kh) ^ (row & 7)) << 4;
        a[mt] = *(const bf16x8_t*)(cA + row * 128 + phys);
      }
      #pragma unroll
      for (int nt = 0; nt < 4; nt++) {
        const int row  = wc * 64 + nt * 16 + ln;
        const int phys = ((ks2 * 4 + kh) ^ (row & 7)) << 4;
        bfr[nt] = *(const bf16x8_t*)(cB + row * 128 + phys);
      }
      #pragma unroll
      for (int mt = 0; mt < 4; mt++)
        #pragma unroll
        for (int nt = 0; nt < 4; nt++)
          acc[mt][nt] = __builtin_amdgcn_mfma_f32_16x16x32_bf16(
              a[mt], bfr[nt], acc[mt][nt], 0, 0, 0);
    }
    __syncthreads();   // drains prefetch vmcnt + compute lgkm; buffers swap
    cur ^= 1;
  }
#undef STAGE_TILES

  // ---- BN partials: column sums over this block's 128 rows ----
  #pragma unroll
  for (int nt = 0; nt < 4; nt++) {
    float s = 0.f, q = 0.f;
    #pragma unroll
    for (int mt = 0; mt < 4; mt++)
      #pragma unroll
      for (int j = 0; j < 4; j++) {
        const float v = acc[mt][nt][j];
        s += v; q += v * v;
      }
    s += __shfl_xor(s, 16); s += __shfl_xor(s, 32);
    q += __shfl_xor(q, 16); q += __shfl_xor(q, 32);
    if (kh == 0) {
      atomicAdd(&psum[wc * 64 + nt * 16 + ln], s);
      atomicAdd(&psumsq[wc * 64 + nt * 16 + ln], q);
    }
  }

  // ---- C scatter via qm (C/D: col=lane&15, row=(lane>>4)*4+reg) ----
  #pragma unroll
  for (int mt = 0; mt < 4; mt++) {
    #pragma unroll
    for (int j = 0; j < 4; j++) {
      const int r = wr * 64 + mt * 16 + kh * 4 + j;
      const size_t ob = (size_t)qm[r] * COUT + wc * 64 + ln;
      #pragma unroll
      for (int nt = 0; nt < 4; nt++)
        out[ob + nt * 16] = acc[mt][nt][j];
    }
  }
}

// ---------------------------------------------------------------------------
// K2_old: R14 fused kernel (fallback when workspace too small for wfg)
// ---------------------------------------------------------------------------
__global__ __launch_bounds__(256, 5) void k2_old(
    const float4* __restrict__ xyzs, const unsigned short* __restrict__ fsorted,
    const float* __restrict__ kpts, const int* __restrict__ cellstart,
    const int* __restrict__ qorder, const unsigned short* __restrict__ Wt,
    float* __restrict__ out, float* __restrict__ psum,
    float* __restrict__ psumsq)
{
  __shared__ char smraw[32000] __attribute__((aligned(16)));
  float4*         Pu   = (float4*)smraw;
  unsigned short* cpos = (unsigned short*)(smraw + 6400);
  short (*S)[SP]       = (short(*)[SP])(smraw + 6400);
  short (*FT)[SP]      = (short(*)[SP])(smraw + 26880);

  __shared__ float4 qd[16];
  __shared__ int    qm[16];
  __shared__ float  kp[NKP][4];
  __shared__ int    Tsh;
  __shared__ int    ucnt;

  const int tid = threadIdx.x;
  const int w   = tid >> 6;
  const int L   = tid & 63;
  const int m0  = blockIdx.x * 16;
  const int b   = m0 >> 12;

  if (tid >= 64 && tid < 64 + NKP) {
    const int k = tid - 64;
    const float kx = kpts[k * 3], ky = kpts[k * 3 + 1], kz = kpts[k * 3 + 2];
    kp[k][0] = -2.f * kx; kp[k][1] = -2.f * ky; kp[k][2] = -2.f * kz;
    kp[k][3] = kx * kx + ky * ky + kz * kz;
  }

  if (tid < 64) {
    int cxm = 12, cym = 12, czm = 12, cxM = -1, cyM = -1, czM = -1;
    if (tid < 16) {
      const float4 Q = xyzs[m0 + tid];
      qd[tid] = Q;
      qm[tid] = qorder[m0 + tid];
      int a = (int)(Q.x * 12.f); a = a > 11 ? 11 : a;
      int c = (int)(Q.y * 12.f); c = c > 11 ? 11 : c;
      int d = (int)(Q.z * 12.f); d = d > 11 ? 11 : d;
      cxm = cxM = a; cym = cyM = c; czm = czM = d;
    }
    #pragma unroll
    for (int off = 8; off >= 1; off >>= 1) {
      int v;
      v = __shfl_xor(cxm, off); cxm = v < cxm ? v : cxm;
      v = __shfl_xor(cxM, off); cxM = v > cxM ? v : cxM;
      v = __shfl_xor(cym, off); cym = v < cym ? v : cym;
      v = __shfl_xor(cyM, off); cyM = v > cyM ? v : cyM;
      v = __shfl_xor(czm, off); czm = v < czm ? v : czm;
      v = __shfl_xor(czM, off); czM = v > czM ? v : czM;
    }
    cxm = __shfl(cxm, 0); cxM = __shfl(cxM, 0);
    cym = __shfl(cym, 0); cyM = __shfl(cyM, 0);
    czm = __shfl(czm, 0); czM = __shfl(czM, 0);

    const int x0 = cxm > 0 ? cxm - 1 : 0, x1 = cxM < 11 ? cxM + 1 : 11;
    const int y0 = cym > 0 ? cym - 1 : 0, y1 = cyM < 11 ? cyM + 1 : 11;
    const int z0 = czm > 0 ? czm - 1 : 0, z1 = czM < 11 ? czM + 1 : 11;
    const int yspan = y1 - y0 + 1;
    int nr = yspan * (z1 - z0 + 1);
    nr = nr > 64 ? 64 : nr;

    int rs = 0, len = 0;
    if (tid < nr) {
      const int zz = z0 + tid / yspan, yy = y0 + tid % yspan;
      const int base = b * 1729 + (zz * 12 + yy) * 12;
      rs  = cellstart[base + x0];
      len = cellstart[base + x1 + 1] - rs;
    }
    int incl = len;
    #pragma unroll
    for (int off = 1; off < 64; off <<= 1) {
      const int v = __shfl_up(incl, off);
      if (tid >= off) incl += v;
    }
    const int excl = incl - len;
    for (int i = 0; i < len; i++) cpos[excl + i] = (unsigned short)(rs + i);
    if (tid == 63) Tsh = incl;
    if (tid == 62) ucnt = 0;
  }
  __syncthreads();
  const int T = Tsh;

  for (int tb = 0; tb < T; tb += 256) {
    const int t = tb + tid;
    if (t < T) {
      const int pos = (int)cpos[t];
      const float4 P = xyzs[b * NPTS + pos];
      float best = 1e9f;
      #pragma unroll
      for (int i = 0; i < 16; i++) {
        const float4 Q = qd[i];
        const float dx = P.x - Q.x, dy = P.y - Q.y, dz = P.z - Q.z;
        const float d2 = dx * dx + dy * dy + dz * dz;
        best = d2 < best ? d2 : best;
      }
      if (best <= R2EFF) {
        const int slot = atomicAdd(&ucnt, 1);
        if (slot < UCAP)
          Pu[slot] = make_float4(P.x, P.y, P.z, __int_as_float(pos));
      }
    }
  }
  __syncthreads();
  int U = ucnt; U = U > UCAP ? UCAP : U;

  const int ln = L & 15;
  const int kh = L >> 4;
  const int qh = tid >> 5;
  const int nn = tid & 31;

  f32x4_t acc[16];
  #pragma unroll
  for (int mt = 0; mt < 16; mt++) acc[mt] = (f32x4_t){0.f, 0.f, 0.f, 0.f};

  for (int ub = 0; ub < U; ub += 32) {
    {
      const int c  = tid & 63;
      const int i0 = tid >> 6;
      #pragma unroll
      for (int ii = 0; ii < 8; ii++) {
        const int i = ii * 4 + i0;
        const int u = ub + i;
        short v = 0;
        if (u < U) {
          const int pos = __float_as_int(Pu[u].w);
          v = (short)fsorted[(size_t)(b * NPTS + pos) * CIN + c];
        }
        FT[c][i] = v;
      }
    }
    bf16x8_t bb;
    #pragma unroll
    for (int half = 0; half < 2; half++) {
      {
        const int u = ub + nn;
        if (u < U) {
          const float4 P = Pu[u];
          const float4 Q = qd[half * 8 + qh];
          const float rx = P.x - Q.x, ry = P.y - Q.y, rz = P.z - Q.z;
          const float rr = rx * rx + ry * ry + rz * rz;
          #pragma unroll
          for (int k = 0; k < NKP; k++) {
            float d2 = fmaf(kp[k][0], rx,
                       fmaf(kp[k][1], ry,
                       fmaf(kp[k][2], rz, rr + kp[k][3])));
            d2 = fmaxf(d2, 0.f);
            const float wv =
                fmaxf(fmaf(-KP_INV, __builtin_amdgcn_sqrtf(d2), 1.f), 0.f);
            S[qh * 16 + k][nn] = (short)f2bf_fast(wv);
          }
          S[qh * 16 + 15][nn] = 0;
        } else {
          #pragma unroll
          for (int k = 0; k < 16; k++) S[qh * 16 + k][nn] = 0;
        }
      }
      __syncthreads();
      if (half == 0) bb = *(const bf16x8_t*)&FT[w * 16 + ln][kh * 8];
      #pragma unroll
      for (int mt = 0; mt < 8; mt++) {
        bf16x8_t aa = *(const bf16x8_t*)&S[mt * 16 + ln][kh * 8];
        acc[half * 8 + mt] =
            __builtin_amdgcn_mfma_f32_16x16x32_bf16(aa, bb, acc[half * 8 + mt],
                                                    0, 0, 0);
      }
      __syncthreads();
    }
  }

  {
    const int c = w * 16 + ln;
    #pragma unroll
    for (int mt = 0; mt < 16; mt++) {
      #pragma unroll
      for (int j = 0; j < 4; j++) {
        const int k = kh * 4 + j;
        if (k < 15) {
          const int byteo = (mt * WFROW + ((k * 64 + c) << 1)) ^ ((mt & 7) << 4);
          *(unsigned short*)(smraw + byteo) = f2bf_fast(acc[mt][j]);
        }
      }
    }
  }
  __syncthreads();

  const int colbase = w * 32;
  f32x4_t acc2[2];
  acc2[0] = (f32x4_t){0.f, 0.f, 0.f, 0.f};
  acc2[1] = (f32x4_t){0.f, 0.f, 0.f, 0.f};

  const unsigned short* Bp0 = &Wt[(size_t)(colbase + ln) * KCP + kh * 8];
  const unsigned short* Bp1 = Bp0 + 16 * KCP;
  const char* wfb = (const char*)smraw + ln * WFROW;
  const int   sw  = (ln & 7) << 4;

  #pragma unroll 6
  for (int kk = 0; kk < 30; kk++) {
    const int ko  = kk * 32;
    const int inr = (kh * 16 + kk * 64) ^ sw;
    bf16x8_t b0 = *(const bf16x8_t*)(Bp0 + ko);
    bf16x8_t b1 = *(const bf16x8_t*)(Bp1 + ko);
    bf16x8_t a0 = *(const bf16x8_t*)(wfb + inr);
    acc2[0] = __builtin_amdgcn_mfma_f32_16x16x32_bf16(a0, b0, acc2[0], 0, 0, 0);
    acc2[1] = __builtin_amdgcn_mfma_f32_16x16x32_bf16(a0, b1, acc2[1], 0, 0, 0);
  }

  float s0 = 0.f, q0 = 0.f, s1 = 0.f, q1 = 0.f;
  #pragma unroll
  for (int j = 0; j < 4; j++) {
    s0 += acc2[0][j]; q0 += acc2[0][j] * acc2[0][j];
    s1 += acc2[1][j]; q1 += acc2[1][j] * acc2[1][j];
  }
  s0 += __shfl_xor(s0, 16); s0 += __shfl_xor(s0, 32);
  q0 += __shfl_xor(q0, 16); q0 += __shfl_xor(q0, 32);
  s1 += __shfl_xor(s1, 16); s1 += __shfl_xor(s1, 32);
  q1 += __shfl_xor(q1, 16); q1 += __shfl_xor(q1, 32);
  if (kh == 0) {
    atomicAdd(&psum[colbase + ln], s0);
    atomicAdd(&psumsq[colbase + ln], q0);
    atomicAdd(&psum[colbase + 16 + ln], s1);
    atomicAdd(&psumsq[colbase + 16 + ln], q1);
  }

  #pragma unroll
  for (int c = 0; c < 2; c++) {
    #pragma unroll
    for (int j = 0; j < 4; j++) {
      const int row = kh * 4 + j;
      out[(size_t)qm[row] * COUT + colbase + c * 16 + ln] = acc2[c][j];
    }
  }
}

// ---------------------------------------------------------------------------
// K4: BN finalize (per-block, from psum) + normalize + LeakyReLU
// ---------------------------------------------------------------------------
__global__ __launch_bounds__(256) void k4_norm(
    float* __restrict__ out, const float* __restrict__ psum,
    const float* __restrict__ psumsq, const float* __restrict__ gamma,
    const float* __restrict__ beta)
{
  __shared__ float a_s[128], b_s[128];
  if (threadIdx.x < 128) {
    const int d = threadIdx.x;
    double mu  = (double)psum[d] / (double)M_TOT;
    double var = (double)psumsq[d] / (double)M_TOT - mu * mu;  // biased
    float rstd = (float)(1.0 / sqrt(var + 1e-5));
    float a = rstd * gamma[d];
    a_s[d] = a;
    b_s[d] = beta[d] - (float)mu * a;
  }
  __syncthreads();
  const int idx = blockIdx.x * 256 + threadIdx.x;   // float4 index
  float4 v = ((const float4*)out)[idx];
  const int d0 = (idx * 4) & 127;
  float y0 = v.x * a_s[d0 + 0] + b_s[d0 + 0];
  float y1 = v.y * a_s[d0 + 1] + b_s[d0 + 1];
  float y2 = v.z * a_s[d0 + 2] + b_s[d0 + 2];
  float y3 = v.w * a_s[d0 + 3] + b_s[d0 + 3];
  v.x = y0 >= 0.f ? y0 : NEG_SLOPE * y0;
  v.y = y1 >= 0.f ? y1 : NEG_SLOPE * y1;
  v.z = y2 >= 0.f ? y2 : NEG_SLOPE * y2;
  v.w = y3 >= 0.f ? y3 : NEG_SLOPE * y3;
  ((float4*)out)[idx] = v;
}

// ---------------------------------------------------------------------------
extern "C" void kernel_launch(void* const* d_in, const int* in_sizes, int n_in,
                              void* d_out, int out_size, void* d_ws,
                              size_t ws_size, hipStream_t stream)
{
  const float* xyz   = (const float*)d_in[0];
  const float* feats = (const float*)d_in[1];
  const float* kpts  = (const float*)d_in[2];
  const float* W     = (const float*)d_in[3];
  const float* gamma = (const float*)d_in[4];
  const float* beta  = (const float*)d_in[5];
  float* out = (float*)d_out;

  char* ws = (char*)d_ws;
  int*            cellcnt   = (int*)(ws + 0);           //  55296 B ─┐
  int*            cellfill  = (int*)(ws + 55296);       //  55296 B  │ zeroed
  float*          psum      = (float*)(ws + 110592);    //    512 B  │
  float*          psumsq    = (float*)(ws + 111104);    //    512 B ─┘
  int*            cellstart = (int*)(ws + 111616);      //  55424 B
  int*            qorder    = (int*)(ws + 167040);      // 131072 B
  float4*         xyzs      = (float4*)(ws + 298112);   // 524288 B
  unsigned short* fsorted   = (unsigned short*)(ws + 822400);   // 4194304 B
  unsigned short* Wtbuf     = (unsigned short*)(ws + 5016704);  // 245760 B
  unsigned short* wfg       = (unsigned short*)(ws + 5262464);  // 62914560 B

  const size_t NEED = 5262464ull + 62914560ull;   // 68,177,024 B

  hipMemsetAsync(ws, 0, 111616, stream);

  if (ws_size >= NEED) {
    k0a_hist    <<< 128, 256, 0, stream>>>(xyz, cellcnt);
    k0b_scan_kW <<<  40, 256, 0, stream>>>(cellcnt, cellstart, W, Wtbuf);
    k0c_scatter <<< 128, 256, 0, stream>>>(xyz, feats, cellstart, cellfill,
                                           qorder, xyzs, fsorted);
    k2a_conv    <<<2048, 256, 0, stream>>>(xyzs, fsorted, kpts, cellstart,
                                           wfg);
    k2b_gemm    <<< 256, 256, 0, stream>>>(wfg, Wtbuf, qorder, out,
                                           psum, psumsq);
    k4_norm     <<<(out_size / 4) / 256, 256, 0, stream>>>(out, psum, psumsq,
                                                           gamma, beta);
  } else {
    k0a_hist    <<< 128, 256, 0, stream>>>(xyz, cellcnt);
    k0b_scan_kW <<<  40, 256, 0, stream>>>(cellcnt, cellstart, W, Wtbuf);
    k0c_scatter <<< 128, 256, 0, stream>>>(xyz, feats, cellstart, cellfill,
                                           qorder, xyzs, fsorted);
    k2_old      <<<2048, 256, 0, stream>>>(xyzs, fsorted, kpts, cellstart,
                                           qorder, Wtbuf, out, psum, psumsq);
    k4_norm     <<<(out_size / 4) / 256, 256, 0, stream>>>(out, psum, psumsq,
                                                           gamma, beta);
  }
}

// Round 12
// 171.572 us; speedup vs baseline: 1.0823x; 1.0823x over previous
//
#include <hip/hip_runtime.h>

// KPConv simple block: grid + block-union MFMA KPConv + BN + LeakyReLU
// B=8, N=4096 -> M=32768; C_IN=64, C_OUT=128, K=15 kernel pts.
//
// Exact simplification: influence w = max(1 - d/0.04, 0) with ||kp||<=0.042
// => candidates with ||rel|| >= 0.082 contribute 0 to every kernel point.
//
// R24 = R20 restored verbatim (proven best: e2e 170.0 us).
// History: R21 (k2b BM=64 re-tile) +15us; R22 (per-lane early-outs) +4us;
// R23 (chunk-coherent skip) +16us. Conclusion: k2a is dependency-latency-
// bound, NOT VALU-issue-bound — any instructions added to the chunk loop's
// serial path cost more than the VALU they save. Bank the optimum:
//  - k2a: search+stage-1, LDS wf writeback, coalesced uint4 dump to wfg,
//    XCD batch swizzle (FETCH 17->8 MB).
//  - k2b: 256-block 128x128x64 tiled GEMM, glds staging, dbuf prefetch,
//    pre-swizzled-source XOR involution (stage-2 67.6 -> ~33 us vs R18).

#define NB     8
#define NPTS   4096
#define M_TOT  32768
#define CIN    64
#define COUT   128
#define NKP    15
#define NCELL  1728            // 12^3
#define UCAP   400             // union cap (mean ~70)
#define R2EFF  (0.082f * 0.082f)
#define KP_INV 25.0f           // 1 / KP_EXTENT(0.04)
#define NEG_SLOPE 0.2f
#define KCP    960             // kc' = k*64+c, k-major, k=15 dropped
#define WFROW  1920            // wf row stride bytes (960 bf16)
#define SP     40              // S/FT row stride (shorts), 80B

typedef float f32x4_t __attribute__((ext_vector_type(4)));
typedef short bf16x8_t __attribute__((ext_vector_type(8)));

__device__ __forceinline__ unsigned short f2bf(float f) {
  union { float f; unsigned u; } v; v.f = f;
  unsigned r = v.u + 0x7FFF + ((v.u >> 16) & 1);   // RNE
  return (unsigned short)(r >> 16);
}
// half-up rounding: same 0.5 ulp max error as RNE, 2 VALU ops
__device__ __forceinline__ unsigned short f2bf_fast(float f) {
  union { float f; unsigned u; } v; v.f = f;
  return (unsigned short)((v.u + 0x8000u) >> 16);
}
__device__ __forceinline__ int cell_of(float x, float y, float z) {
  int cx = (int)(x * 12.f); cx = cx > 11 ? 11 : cx;
  int cy = (int)(y * 12.f); cy = cy > 11 ? 11 : cy;
  int cz = (int)(z * 12.f); cz = cz > 11 ? 11 : cz;
  return (cz * 12 + cy) * 12 + cx;
}
// async global->LDS, 16B per lane; LDS dest = uniform base + lane*16
__device__ __forceinline__ void gld_lds16(const unsigned short* g, void* l) {
  __builtin_amdgcn_global_load_lds(
      (const __attribute__((address_space(1))) unsigned int*)g,
      (__attribute__((address_space(3))) unsigned int*)l, 16, 0, 0);
}

// ---------------------------------------------------------------------------
// K0a: per-cell histogram
// ---------------------------------------------------------------------------
__global__ __launch_bounds__(256) void k0a_hist(
    const float* __restrict__ xyz, int* __restrict__ cellcnt)
{
  const int pt = blockIdx.x * 256 + threadIdx.x;
  const float x = xyz[pt * 3], y = xyz[pt * 3 + 1], z = xyz[pt * 3 + 2];
  const int b = pt >> 12;
  atomicAdd(&cellcnt[b * NCELL + cell_of(x, y, z)], 1);
}

// ---------------------------------------------------------------------------
// K0b: blocks 0..7 = per-batch exclusive scan; blocks 8..39 = W -> Wt
// Wt[d][k*64+c] bf16, k-major, k=15 dropped.
// ---------------------------------------------------------------------------
__global__ __launch_bounds__(256) void k0b_scan_kW(
    const int* __restrict__ cellcnt, int* __restrict__ cellstart,
    const float* __restrict__ W, unsigned short* __restrict__ Wt)
{
  if (blockIdx.x >= 8) {
    const int idx = (blockIdx.x - 8) * 256 + threadIdx.x;  // 8192
    const int c = idx & 63, d = idx >> 6;                  // d 0..127
    #pragma unroll
    for (int k = 0; k < NKP; k++)
      Wt[(size_t)d * KCP + k * 64 + c] =
          f2bf(W[(size_t)k * (CIN * COUT) + c * COUT + d]);
    return;
  }
  __shared__ int ps[256];
  const int b = blockIdx.x, t = threadIdx.x;
  int local[7], s = 0;
  #pragma unroll
  for (int i = 0; i < 7; i++) {
    const int cid = t * 7 + i;
    const int c = (cid < NCELL) ? cellcnt[b * NCELL + cid] : 0;
    local[i] = c; s += c;
  }
  ps[t] = s; __syncthreads();
  for (int off = 1; off < 256; off <<= 1) {
    int v = (t >= off) ? ps[t - off] : 0;
    __syncthreads();
    ps[t] += v;
    __syncthreads();
  }
  int run = ps[t] - s;
  #pragma unroll
  for (int i = 0; i < 7; i++) {
    const int cid = t * 7 + i;
    if (cid < NCELL) { cellstart[b * 1729 + cid] = run; run += local[i]; }
  }
  if (t == 255) cellstart[b * 1729 + NCELL] = ps[255];
}

// ---------------------------------------------------------------------------
// K0c: counting-sort scatter -> qorder + sorted xyz + sorted bf16 feats
// ---------------------------------------------------------------------------
__global__ __launch_bounds__(256) void k0c_scatter(
    const float* __restrict__ xyz, const float* __restrict__ feats,
    const int* __restrict__ cellstart, int* __restrict__ cellfill,
    int* __restrict__ qorder, float4* __restrict__ xyzs,
    unsigned short* __restrict__ fsorted)
{
  const int pt = blockIdx.x * 256 + threadIdx.x;
  const float x = xyz[pt * 3], y = xyz[pt * 3 + 1], z = xyz[pt * 3 + 2];
  const int b = pt >> 12;
  const int cid = cell_of(x, y, z);
  const int slot = atomicAdd(&cellfill[b * NCELL + cid], 1);
  const int pos = b * NPTS + cellstart[b * 1729 + cid] + slot;
  qorder[pos] = pt;
  xyzs[pos] = make_float4(x, y, z, 0.f);
  const float* src = &feats[(size_t)pt * CIN];
  uint4* dst = (uint4*)&fsorted[(size_t)pos * CIN];
  #pragma unroll
  for (int g = 0; g < 8; g++) {
    float4 a = *(const float4*)(src + g * 8);
    float4 c = *(const float4*)(src + g * 8 + 4);
    union { unsigned short s[8]; uint4 v; } u;
    u.s[0] = f2bf(a.x); u.s[1] = f2bf(a.y); u.s[2] = f2bf(a.z); u.s[3] = f2bf(a.w);
    u.s[4] = f2bf(c.x); u.s[5] = f2bf(c.y); u.s[6] = f2bf(c.z); u.s[7] = f2bf(c.w);
    dst[g] = u.v;
  }
}

// ---------------------------------------------------------------------------
// K2a: search + stage-1, result -> wfg[32768][960] bf16 (coalesced dump)
// ---------------------------------------------------------------------------
__global__ __launch_bounds__(256, 5) void k2a_conv(
    const float4* __restrict__ xyzs, const unsigned short* __restrict__ fsorted,
    const float* __restrict__ kpts, const int* __restrict__ cellstart,
    unsigned short* __restrict__ wfg)
{
  // phase-aliased LDS (32000 B):
  //   [0..6400)       Pu[400] float4
  //   [6400..14592)   cpos[4096] ushort
  //   [6400..26880)   S[128][40] short
  //   [26880..32000)  FT[64][40] short
  //   [0..30720)      wf 16 x 1920 B (XOR-swizzled; writeback+dump)
  __shared__ char smraw[32000] __attribute__((aligned(16)));
  float4*         Pu   = (float4*)smraw;
  unsigned short* cpos = (unsigned short*)(smraw + 6400);
  short (*S)[SP]       = (short(*)[SP])(smraw + 6400);
  short (*FT)[SP]      = (short(*)[SP])(smraw + 26880);

  __shared__ float4 qd[16];
  __shared__ float  kp[NKP][4];   // (-2kx, -2ky, -2kz, |kp|^2)
  __shared__ int    Tsh;
  __shared__ int    ucnt;

  const int tid = threadIdx.x;
  const int w   = tid >> 6;
  const int L   = tid & 63;
  // XCD batch swizzle: XCD x (= bid&7) owns tiles [x*256, x*256+256) ==
  // batch x exactly -> per-XCD gather set (fsorted 512KB + xyzs 64KB) L2-hot.
  const int tile = ((blockIdx.x & 7) << 8) | (blockIdx.x >> 3);
  const int m0  = tile * 16;
  const int b   = blockIdx.x & 7;

  if (tid >= 64 && tid < 64 + NKP) {
    const int k = tid - 64;
    const float kx = kpts[k * 3], ky = kpts[k * 3 + 1], kz = kpts[k * 3 + 2];
    kp[k][0] = -2.f * kx; kp[k][1] = -2.f * ky; kp[k][2] = -2.f * kz;
    kp[k][3] = kx * kx + ky * ky + kz * kz;
  }

  // ---- wave-0 prologue: bbox -> row ranges -> pfx (shfl scan) -> cpos ----
  if (tid < 64) {
    int cxm = 12, cym = 12, czm = 12, cxM = -1, cyM = -1, czM = -1;
    if (tid < 16) {
      const float4 Q = xyzs[m0 + tid];
      qd[tid] = Q;
      int a = (int)(Q.x * 12.f); a = a > 11 ? 11 : a;
      int c = (int)(Q.y * 12.f); c = c > 11 ? 11 : c;
      int d = (int)(Q.z * 12.f); d = d > 11 ? 11 : d;
      cxm = cxM = a; cym = cyM = c; czm = czM = d;
    }
    #pragma unroll
    for (int off = 8; off >= 1; off >>= 1) {
      int v;
      v = __shfl_xor(cxm, off); cxm = v < cxm ? v : cxm;
      v = __shfl_xor(cxM, off); cxM = v > cxM ? v : cxM;
      v = __shfl_xor(cym, off); cym = v < cym ? v : cym;
      v = __shfl_xor(cyM, off); cyM = v > cyM ? v : cyM;
      v = __shfl_xor(czm, off); czm = v < czm ? v : czm;
      v = __shfl_xor(czM, off); czM = v > czM ? v : czM;
    }
    cxm = __shfl(cxm, 0); cxM = __shfl(cxM, 0);
    cym = __shfl(cym, 0); cyM = __shfl(cyM, 0);
    czm = __shfl(czm, 0); czM = __shfl(czM, 0);

    const int x0 = cxm > 0 ? cxm - 1 : 0, x1 = cxM < 11 ? cxM + 1 : 11;
    const int y0 = cym > 0 ? cym - 1 : 0, y1 = cyM < 11 ? cyM + 1 : 11;
    const int z0 = czm > 0 ? czm - 1 : 0, z1 = czM < 11 ? czM + 1 : 11;
    const int yspan = y1 - y0 + 1;
    int nr = yspan * (z1 - z0 + 1);
    nr = nr > 64 ? 64 : nr;

    int rs = 0, len = 0;
    if (tid < nr) {
      const int zz = z0 + tid / yspan, yy = y0 + tid % yspan;
      const int base = b * 1729 + (zz * 12 + yy) * 12;
      rs  = cellstart[base + x0];
      len = cellstart[base + x1 + 1] - rs;
    }
    int incl = len;
    #pragma unroll
    for (int off = 1; off < 64; off <<= 1) {
      const int v = __shfl_up(incl, off);
      if (tid >= off) incl += v;
    }
    const int excl = incl - len;
    for (int i = 0; i < len; i++) cpos[excl + i] = (unsigned short)(rs + i);
    if (tid == 63) Tsh = incl;
    if (tid == 62) ucnt = 0;
  }
  __syncthreads();
  const int T = Tsh;

  // ---- union search: any-hit over 16 queries, branch-free test ----
  for (int tb = 0; tb < T; tb += 256) {
    const int t = tb + tid;
    if (t < T) {
      const int pos = (int)cpos[t];
      const float4 P = xyzs[b * NPTS + pos];
      float best = 1e9f;
      #pragma unroll
      for (int i = 0; i < 16; i++) {
        const float4 Q = qd[i];
        const float dx = P.x - Q.x, dy = P.y - Q.y, dz = P.z - Q.z;
        const float d2 = dx * dx + dy * dy + dz * dz;
        best = d2 < best ? d2 : best;
      }
      if (best <= R2EFF) {
        const int slot = atomicAdd(&ucnt, 1);
        if (slot < UCAP)
          Pu[slot] = make_float4(P.x, P.y, P.z, __int_as_float(pos));
      }
    }
  }
  __syncthreads();
  int U = ucnt; U = U > UCAP ? UCAP : U;

  // ---- stage-1: chunked MFMA over the union, two 8-query half-passes ----
  const int ln = L & 15;
  const int kh = L >> 4;
  const int qh = tid >> 5;      // 0..7 local query of this half
  const int nn = tid & 31;      // chunk column

  f32x4_t acc[16];
  #pragma unroll
  for (int mt = 0; mt < 16; mt++) acc[mt] = (f32x4_t){0.f, 0.f, 0.f, 0.f};

  for (int ub = 0; ub < U; ub += 32) {
    // FT[c][i]: sorted bf16 rows (L2-hot, spatially local)
    {
      const int c  = tid & 63;
      const int i0 = tid >> 6;
      #pragma unroll
      for (int ii = 0; ii < 8; ii++) {
        const int i = ii * 4 + i0;
        const int u = ub + i;
        short v = 0;
        if (u < U) {
          const int pos = __float_as_int(Pu[u].w);
          v = (short)fsorted[(size_t)(b * NPTS + pos) * CIN + c];
        }
        FT[c][i] = v;
      }
    }

    bf16x8_t bb;   // FT fragment, reused by both halves
    #pragma unroll
    for (int half = 0; half < 2; half++) {
      // S fill: one (q, n) pair per thread for queries half*8 .. half*8+7
      {
        const int u = ub + nn;
        if (u < U) {
          const float4 P = Pu[u];
          const float4 Q = qd[half * 8 + qh];
          const float rx = P.x - Q.x, ry = P.y - Q.y, rz = P.z - Q.z;
          const float rr = rx * rx + ry * ry + rz * rz;
          #pragma unroll
          for (int k = 0; k < NKP; k++) {
            float d2 = fmaf(kp[k][0], rx,
                       fmaf(kp[k][1], ry,
                       fmaf(kp[k][2], rz, rr + kp[k][3])));
            d2 = fmaxf(d2, 0.f);
            const float wv =
                fmaxf(fmaf(-KP_INV, __builtin_amdgcn_sqrtf(d2), 1.f), 0.f);
            S[qh * 16 + k][nn] = (short)f2bf_fast(wv);
          }
          S[qh * 16 + 15][nn] = 0;
        } else {
          #pragma unroll
          for (int k = 0; k < 16; k++) S[qh * 16 + k][nn] = 0;
        }
      }
      __syncthreads();
      if (half == 0) bb = *(const bf16x8_t*)&FT[w * 16 + ln][kh * 8];
      #pragma unroll
      for (int mt = 0; mt < 8; mt++) {
        bf16x8_t aa = *(const bf16x8_t*)&S[mt * 16 + ln][kh * 8];
        acc[half * 8 + mt] =
            __builtin_amdgcn_mfma_f32_16x16x32_bf16(aa, bb, acc[half * 8 + mt],
                                                    0, 0, 0);
      }
      __syncthreads();
    }
  }

  // ---- writeback: acc -> LDS wf (swizzled; S/FT/Pu dead) ----
  {
    const int c = w * 16 + ln;
    #pragma unroll
    for (int mt = 0; mt < 16; mt++) {
      #pragma unroll
      for (int j = 0; j < 4; j++) {
        const int k = kh * 4 + j;
        if (k < 15) {      // k=15 slot zero: its wfg bytes are covered by
                           // k<15 columns (k*64 spans 0..959), none skipped
          const int byteo = (mt * WFROW + ((k * 64 + c) << 1)) ^ ((mt & 7) << 4);
          *(unsigned short*)(smraw + byteo) = f2bf_fast(acc[mt][j]);
        }
      }
    }
  }
  __syncthreads();

  // ---- dump: LDS wf -> wfg linear, coalesced uint4 (30720 B/block) ----
  for (int i = tid; i < 16 * 120; i += 256) {
    const int r  = i / 120;
    const int ch = i - r * 120;
    const uint4 v =
        *(const uint4*)(smraw + ((r * WFROW + ch * 16) ^ ((r & 7) << 4)));
    *(uint4*)(wfg + (size_t)(m0 + r) * KCP + ch * 8) = v;
  }
}

// ---------------------------------------------------------------------------
// K2b: tiled GEMM out[32768][128] = wfg[32768][960] @ Wt[128][960]^T
// 256 blocks x 128x128 tile, BK=64, 4 waves 2x2 (64x64 each), glds staging,
// double-buffered prefetch. kc accumulation order == R14/R18 (bitwise-same).
// ---------------------------------------------------------------------------
__global__ __launch_bounds__(256, 2) void k2b_gemm(
    const unsigned short* __restrict__ wfg,
    const unsigned short* __restrict__ Wt,
    const int* __restrict__ qorder, float* __restrict__ out,
    float* __restrict__ psum, float* __restrict__ psumsq)
{
  // A/B tiles: [128 rows][64 k] bf16 = 16384 B each, double-buffered.
  // LDS layout linear (glds writes base+lane*16); XOR swizzle achieved by
  // pre-swizzling the GLOBAL source column (involution), ds_read same XOR.
  __shared__ char smA[2][16384] __attribute__((aligned(16)));
  __shared__ char smB[2][16384] __attribute__((aligned(16)));
  __shared__ int  qm[128];

  const int tid = threadIdx.x;
  const int w   = tid >> 6;
  const int L   = tid & 63;
  const int m0  = blockIdx.x * 128;

  if (tid < 128) qm[tid] = qorder[m0 + tid];

  const int c16 = L & 7;

#define STAGE_TILES(buf, ks)                                                 \
  {                                                                          \
    _Pragma("unroll")                                                        \
    for (int i = 0; i < 4; i++) {                                            \
      const int row = (w * 4 + i) * 8 + (L >> 3);                            \
      const int sc  = (c16 ^ (row & 7)) << 3;   /* shorts */                 \
      gld_lds16(wfg + (size_t)(m0 + row) * KCP + (ks) * 64 + sc,             \
                (char*)smA[buf] + (w * 4 + i) * 1024);                       \
      gld_lds16(Wt + (size_t)row * KCP + (ks) * 64 + sc,                     \
                (char*)smB[buf] + (w * 4 + i) * 1024);                       \
    }                                                                        \
  }

  STAGE_TILES(0, 0)
  __syncthreads();

  const int wr = w >> 1, wc = w & 1;
  const int ln = L & 15, kh = L >> 4;

  f32x4_t acc[4][4];
  #pragma unroll
  for (int mt = 0; mt < 4; mt++)
    #pragma unroll
    for (int nt = 0; nt < 4; nt++)
      acc[mt][nt] = (f32x4_t){0.f, 0.f, 0.f, 0.f};

  int cur = 0;
  for (int ks = 0; ks < 15; ks++) {
    if (ks < 14) STAGE_TILES(cur ^ 1, ks + 1)   // prefetch under compute

    const char* cA = smA[cur];
    const char* cB = smB[cur];
    #pragma unroll
    for (int ks2 = 0; ks2 < 2; ks2++) {
      bf16x8_t a[4], bfr[4];
      #pragma unroll
      for (int mt = 0; mt < 4; mt++) {
        const int row  = wr * 64 + mt * 16 + ln;
        const int phys = ((ks2 * 4 + kh) ^ (row & 7)) << 4;
        a[mt] = *(const bf16x8_t*)(cA + row * 128 + phys);
      }
      #pragma unroll
      for (int nt = 0; nt < 4; nt++) {
        const int row  = wc * 64 + nt * 16 + ln;
        const int phys = ((ks2 * 4 + kh) ^ (row & 7)) << 4;
        bfr[nt] = *(const bf16x8_t*)(cB + row * 128 + phys);
      }
      #pragma unroll
      for (int mt = 0; mt < 4; mt++)
        #pragma unroll
        for (int nt = 0; nt < 4; nt++)
          acc[mt][nt] = __builtin_amdgcn_mfma_f32_16x16x32_bf16(
              a[mt], bfr[nt], acc[mt][nt], 0, 0, 0);
    }
    __syncthreads();   // drains prefetch vmcnt + compute lgkm; buffers swap
    cur ^= 1;
  }
#undef STAGE_TILES

  // ---- BN partials: column sums over this block's 128 rows ----
  #pragma unroll
  for (int nt = 0; nt < 4; nt++) {
    float s = 0.f, q = 0.f;
    #pragma unroll
    for (int mt = 0; mt < 4; mt++)
      #pragma unroll
      for (int j = 0; j < 4; j++) {
        const float v = acc[mt][nt][j];
        s += v; q += v * v;
      }
    s += __shfl_xor(s, 16); s += __shfl_xor(s, 32);
    q += __shfl_xor(q, 16); q += __shfl_xor(q, 32);
    if (kh == 0) {
      atomicAdd(&psum[wc * 64 + nt * 16 + ln], s);
      atomicAdd(&psumsq[wc * 64 + nt * 16 + ln], q);
    }
  }

  // ---- C scatter via qm (C/D: col=lane&15, row=(lane>>4)*4+reg) ----
  #pragma unroll
  for (int mt = 0; mt < 4; mt++) {
    #pragma unroll
    for (int j = 0; j < 4; j++) {
      const int r = wr * 64 + mt * 16 + kh * 4 + j;
      const size_t ob = (size_t)qm[r] * COUT + wc * 64 + ln;
      #pragma unroll
      for (int nt = 0; nt < 4; nt++)
        out[ob + nt * 16] = acc[mt][nt][j];
    }
  }
}

// ---------------------------------------------------------------------------
// K2_old: R14 fused kernel (fallback when workspace too small for wfg)
// ---------------------------------------------------------------------------
__global__ __launch_bounds__(256, 5) void k2_old(
    const float4* __restrict__ xyzs, const unsigned short* __restrict__ fsorted,
    const float* __restrict__ kpts, const int* __restrict__ cellstart,
    const int* __restrict__ qorder, const unsigned short* __restrict__ Wt,
    float* __restrict__ out, float* __restrict__ psum,
    float* __restrict__ psumsq)
{
  __shared__ char smraw[32000] __attribute__((aligned(16)));
  float4*         Pu   = (float4*)smraw;
  unsigned short* cpos = (unsigned short*)(smraw + 6400);
  short (*S)[SP]       = (short(*)[SP])(smraw + 6400);
  short (*FT)[SP]      = (short(*)[SP])(smraw + 26880);

  __shared__ float4 qd[16];
  __shared__ int    qm[16];
  __shared__ float  kp[NKP][4];
  __shared__ int    Tsh;
  __shared__ int    ucnt;

  const int tid = threadIdx.x;
  const int w   = tid >> 6;
  const int L   = tid & 63;
  const int m0  = blockIdx.x * 16;
  const int b   = m0 >> 12;

  if (tid >= 64 && tid < 64 + NKP) {
    const int k = tid - 64;
    const float kx = kpts[k * 3], ky = kpts[k * 3 + 1], kz = kpts[k * 3 + 2];
    kp[k][0] = -2.f * kx; kp[k][1] = -2.f * ky; kp[k][2] = -2.f * kz;
    kp[k][3] = kx * kx + ky * ky + kz * kz;
  }

  if (tid < 64) {
    int cxm = 12, cym = 12, czm = 12, cxM = -1, cyM = -1, czM = -1;
    if (tid < 16) {
      const float4 Q = xyzs[m0 + tid];
      qd[tid] = Q;
      qm[tid] = qorder[m0 + tid];
      int a = (int)(Q.x * 12.f); a = a > 11 ? 11 : a;
      int c = (int)(Q.y * 12.f); c = c > 11 ? 11 : c;
      int d = (int)(Q.z * 12.f); d = d > 11 ? 11 : d;
      cxm = cxM = a; cym = cyM = c; czm = czM = d;
    }
    #pragma unroll
    for (int off = 8; off >= 1; off >>= 1) {
      int v;
      v = __shfl_xor(cxm, off); cxm = v < cxm ? v : cxm;
      v = __shfl_xor(cxM, off); cxM = v > cxM ? v : cxM;
      v = __shfl_xor(cym, off); cym = v < cym ? v : cym;
      v = __shfl_xor(cyM, off); cyM = v > cyM ? v : cyM;
      v = __shfl_xor(czm, off); czm = v < czm ? v : czm;
      v = __shfl_xor(czM, off); czM = v > czM ? v : czM;
    }
    cxm = __shfl(cxm, 0); cxM = __shfl(cxM, 0);
    cym = __shfl(cym, 0); cyM = __shfl(cyM, 0);
    czm = __shfl(czm, 0); czM = __shfl(czM, 0);

    const int x0 = cxm > 0 ? cxm - 1 : 0, x1 = cxM < 11 ? cxM + 1 : 11;
    const int y0 = cym > 0 ? cym - 1 : 0, y1 = cyM < 11 ? cyM + 1 : 11;
    const int z0 = czm > 0 ? czm - 1 : 0, z1 = czM < 11 ? czM + 1 : 11;
    const int yspan = y1 - y0 + 1;
    int nr = yspan * (z1 - z0 + 1);
    nr = nr > 64 ? 64 : nr;

    int rs = 0, len = 0;
    if (tid < nr) {
      const int zz = z0 + tid / yspan, yy = y0 + tid % yspan;
      const int base = b * 1729 + (zz * 12 + yy) * 12;
      rs  = cellstart[base + x0];
      len = cellstart[base + x1 + 1] - rs;
    }
    int incl = len;
    #pragma unroll
    for (int off = 1; off < 64; off <<= 1) {
      const int v = __shfl_up(incl, off);
      if (tid >= off) incl += v;
    }
    const int excl = incl - len;
    for (int i = 0; i < len; i++) cpos[excl + i] = (unsigned short)(rs + i);
    if (tid == 63) Tsh = incl;
    if (tid == 62) ucnt = 0;
  }
  __syncthreads();
  const int T = Tsh;

  for (int tb = 0; tb < T; tb += 256) {
    const int t = tb + tid;
    if (t < T) {
      const int pos = (int)cpos[t];
      const float4 P = xyzs[b * NPTS + pos];
      float best = 1e9f;
      #pragma unroll
      for (int i = 0; i < 16; i++) {
        const float4 Q = qd[i];
        const float dx = P.x - Q.x, dy = P.y - Q.y, dz = P.z - Q.z;
        const float d2 = dx * dx + dy * dy + dz * dz;
        best = d2 < best ? d2 : best;
      }
      if (best <= R2EFF) {
        const int slot = atomicAdd(&ucnt, 1);
        if (slot < UCAP)
          Pu[slot] = make_float4(P.x, P.y, P.z, __int_as_float(pos));
      }
    }
  }
  __syncthreads();
  int U = ucnt; U = U > UCAP ? UCAP : U;

  const int ln = L & 15;
  const int kh = L >> 4;
  const int qh = tid >> 5;
  const int nn = tid & 31;

  f32x4_t acc[16];
  #pragma unroll
  for (int mt = 0; mt < 16; mt++) acc[mt] = (f32x4_t){0.f, 0.f, 0.f, 0.f};

  for (int ub = 0; ub < U; ub += 32) {
    {
      const int c  = tid & 63;
      const int i0 = tid >> 6;
      #pragma unroll
      for (int ii = 0; ii < 8; ii++) {
        const int i = ii * 4 + i0;
        const int u = ub + i;
        short v = 0;
        if (u < U) {
          const int pos = __float_as_int(Pu[u].w);
          v = (short)fsorted[(size_t)(b * NPTS + pos) * CIN + c];
        }
        FT[c][i] = v;
      }
    }
    bf16x8_t bb;
    #pragma unroll
    for (int half = 0; half < 2; half++) {
      {
        const int u = ub + nn;
        if (u < U) {
          const float4 P = Pu[u];
          const float4 Q = qd[half * 8 + qh];
          const float rx = P.x - Q.x, ry = P.y - Q.y, rz = P.z - Q.z;
          const float rr = rx * rx + ry * ry + rz * rz;
          #pragma unroll
          for (int k = 0; k < NKP; k++) {
            float d2 = fmaf(kp[k][0], rx,
                       fmaf(kp[k][1], ry,
                       fmaf(kp[k][2], rz, rr + kp[k][3])));
            d2 = fmaxf(d2, 0.f);
            const float wv =
                fmaxf(fmaf(-KP_INV, __builtin_amdgcn_sqrtf(d2), 1.f), 0.f);
            S[qh * 16 + k][nn] = (short)f2bf_fast(wv);
          }
          S[qh * 16 + 15][nn] = 0;
        } else {
          #pragma unroll
          for (int k = 0; k < 16; k++) S[qh * 16 + k][nn] = 0;
        }
      }
      __syncthreads();
      if (half == 0) bb = *(const bf16x8_t*)&FT[w * 16 + ln][kh * 8];
      #pragma unroll
      for (int mt = 0; mt < 8; mt++) {
        bf16x8_t aa = *(const bf16x8_t*)&S[mt * 16 + ln][kh * 8];
        acc[half * 8 + mt] =
            __builtin_amdgcn_mfma_f32_16x16x32_bf16(aa, bb, acc[half * 8 + mt],
                                                    0, 0, 0);
      }
      __syncthreads();
    }
  }

  {
    const int c = w * 16 + ln;
    #pragma unroll
    for (int mt = 0; mt < 16; mt++) {
      #pragma unroll
      for (int j = 0; j < 4; j++) {
        const int k = kh * 4 + j;
        if (k < 15) {
          const int byteo = (mt * WFROW + ((k * 64 + c) << 1)) ^ ((mt & 7) << 4);
          *(unsigned short*)(smraw + byteo) = f2bf_fast(acc[mt][j]);
        }
      }
    }
  }
  __syncthreads();

  const int colbase = w * 32;
  f32x4_t acc2[2];
  acc2[0] = (f32x4_t){0.f, 0.f, 0.f, 0.f};
  acc2[1] = (f32x4_t){0.f, 0.f, 0.f, 0.f};

  const unsigned short* Bp0 = &Wt[(size_t)(colbase + ln) * KCP + kh * 8];
  const unsigned short* Bp1 = Bp0 + 16 * KCP;
  const char* wfb = (const char*)smraw + ln * WFROW;
  const int   sw  = (ln & 7) << 4;

  #pragma unroll 6
  for (int kk = 0; kk < 30; kk++) {
    const int ko  = kk * 32;
    const int inr = (kh * 16 + kk * 64) ^ sw;
    bf16x8_t b0 = *(const bf16x8_t*)(Bp0 + ko);
    bf16x8_t b1 = *(const bf16x8_t*)(Bp1 + ko);
    bf16x8_t a0 = *(const bf16x8_t*)(wfb + inr);
    acc2[0] = __builtin_amdgcn_mfma_f32_16x16x32_bf16(a0, b0, acc2[0], 0, 0, 0);
    acc2[1] = __builtin_amdgcn_mfma_f32_16x16x32_bf16(a0, b1, acc2[1], 0, 0, 0);
  }

  float s0 = 0.f, q0 = 0.f, s1 = 0.f, q1 = 0.f;
  #pragma unroll
  for (int j = 0; j < 4; j++) {
    s0 += acc2[0][j]; q0 += acc2[0][j] * acc2[0][j];
    s1 += acc2[1][j]; q1 += acc2[1][j] * acc2[1][j];
  }
  s0 += __shfl_xor(s0, 16); s0 += __shfl_xor(s0, 32);
  q0 += __shfl_xor(q0, 16); q0 += __shfl_xor(q0, 32);
  s1 += __shfl_xor(s1, 16); s1 += __shfl_xor(s1, 32);
  q1 += __shfl_xor(q1, 16); q1 += __shfl_xor(q1, 32);
  if (kh == 0) {
    atomicAdd(&psum[colbase + ln], s0);
    atomicAdd(&psumsq[colbase + ln], q0);
    atomicAdd(&psum[colbase + 16 + ln], s1);
    atomicAdd(&psumsq[colbase + 16 + ln], q1);
  }

  #pragma unroll
  for (int c = 0; c < 2; c++) {
    #pragma unroll
    for (int j = 0; j < 4; j++) {
      const int row = kh * 4 + j;
      out[(size_t)qm[row] * COUT + colbase + c * 16 + ln] = acc2[c][j];
    }
  }
}

// ---------------------------------------------------------------------------
// K4: BN finalize (per-block, from psum) + normalize + LeakyReLU
// ---------------------------------------------------------------------------
__global__ __launch_bounds__(256) void k4_norm(
    float* __restrict__ out, const float* __restrict__ psum,
    const float* __restrict__ psumsq, const float* __restrict__ gamma,
    const float* __restrict__ beta)
{
  __shared__ float a_s[128], b_s[128];
  if (threadIdx.x < 128) {
    const int d = threadIdx.x;
    double mu  = (double)psum[d] / (double)M_TOT;
    double var = (double)psumsq[d] / (double)M_TOT - mu * mu;  // biased
    float rstd = (float)(1.0 / sqrt(var + 1e-5));
    float a = rstd * gamma[d];
    a_s[d] = a;
    b_s[d] = beta[d] - (float)mu * a;
  }
  __syncthreads();
  const int idx = blockIdx.x * 256 + threadIdx.x;   // float4 index
  float4 v = ((const float4*)out)[idx];
  const int d0 = (idx * 4) & 127;
  float y0 = v.x * a_s[d0 + 0] + b_s[d0 + 0];
  float y1 = v.y * a_s[d0 + 1] + b_s[d0 + 1];
  float y2 = v.z * a_s[d0 + 2] + b_s[d0 + 2];
  float y3 = v.w * a_s[d0 + 3] + b_s[d0 + 3];
  v.x = y0 >= 0.f ? y0 : NEG_SLOPE * y0;
  v.y = y1 >= 0.f ? y1 : NEG_SLOPE * y1;
  v.z = y2 >= 0.f ? y2 : NEG_SLOPE * y2;
  v.w = y3 >= 0.f ? y3 : NEG_SLOPE * y3;
  ((float4*)out)[idx] = v;
}

// ---------------------------------------------------------------------------
extern "C" void kernel_launch(void* const* d_in, const int* in_sizes, int n_in,
                              void* d_out, int out_size, void* d_ws,
                              size_t ws_size, hipStream_t stream)
{
  const float* xyz   = (const float*)d_in[0];
  const float* feats = (const float*)d_in[1];
  const float* kpts  = (const float*)d_in[2];
  const float* W     = (const float*)d_in[3];
  const float* gamma = (const float*)d_in[4];
  const float* beta  = (const float*)d_in[5];
  float* out = (float*)d_out;

  char* ws = (char*)d_ws;
  int*            cellcnt   = (int*)(ws + 0);           //  55296 B ─┐
  int*            cellfill  = (int*)(ws + 55296);       //  55296 B  │ zeroed
  float*          psum      = (float*)(ws + 110592);    //    512 B  │
  float*          psumsq    = (float*)(ws + 111104);    //    512 B ─┘
  int*            cellstart = (int*)(ws + 111616);      //  55424 B
  int*            qorder    = (int*)(ws + 167040);      // 131072 B
  float4*         xyzs      = (float4*)(ws + 298112);   // 524288 B
  unsigned short* fsorted   = (unsigned short*)(ws + 822400);   // 4194304 B
  unsigned short* Wtbuf     = (unsigned short*)(ws + 5016704);  // 245760 B
  unsigned short* wfg       = (unsigned short*)(ws + 5262464);  // 62914560 B

  const size_t NEED = 5262464ull + 62914560ull;   // 68,177,024 B

  hipMemsetAsync(ws, 0, 111616, stream);

  if (ws_size >= NEED) {
    k0a_hist    <<< 128, 256, 0, stream>>>(xyz, cellcnt);
    k0b_scan_kW <<<  40, 256, 0, stream>>>(cellcnt, cellstart, W, Wtbuf);
    k0c_scatter <<< 128, 256, 0, stream>>>(xyz, feats, cellstart, cellfill,
                                           qorder, xyzs, fsorted);
    k2a_conv    <<<2048, 256, 0, stream>>>(xyzs, fsorted, kpts, cellstart,
                                           wfg);
    k2b_gemm    <<< 256, 256, 0, stream>>>(wfg, Wtbuf, qorder, out,
                                           psum, psumsq);
    k4_norm     <<<(out_size / 4) / 256, 256, 0, stream>>>(out, psum, psumsq,
                                                           gamma, beta);
  } else {
    k0a_hist    <<< 128, 256, 0, stream>>>(xyz, cellcnt);
    k0b_scan_kW <<<  40, 256, 0, stream>>>(cellcnt, cellstart, W, Wtbuf);
    k0c_scatter <<< 128, 256, 0, stream>>>(xyz, feats, cellstart, cellfill,
                                           qorder, xyzs, fsorted);
    k2_old      <<<2048, 256, 0, stream>>>(xyzs, fsorted, kpts, cellstart,
                                           qorder, Wtbuf, out, psum, psumsq);
    k4_norm     <<<(out_size / 4) / 256, 256, 0, stream>>>(out, psum, psumsq,
                                                           gamma, beta);
  }
}

// Round 13
// 169.761 us; speedup vs baseline: 1.0938x; 1.0107x over previous
//
#include <hip/hip_runtime.h>

// KPConv simple block: grid + block-union MFMA KPConv + BN + LeakyReLU
// B=8, N=4096 -> M=32768; C_IN=64, C_OUT=128, K=15 kernel pts.
//
// Exact simplification: influence w = max(1 - d/0.04, 0) with ||kp||<=0.042
// => candidates with ||rel|| >= 0.082 contribute 0 to every kernel point.
//
// R25 = R24 (proven 171.6/170.0) + counted-vmcnt pipeline in k2b.
// Differential accounting pins k2b at ~36.5 us vs ~11 us traffic floor:
// its per-step __syncthreads() compiles to vmcnt(0) and drains the
// just-issued prefetch (8 glds, ~600-900cy) at every K-step with 1
// block/CU (nothing covers the wait). Fix = T4 counted wait (m201
// template): wait vmcnt(8) (only the OLDER stage), raw s_barrier,
// second barrier after compute protects the buffer being overwritten
// next iteration. Same buffers, same kc order -> out bitwise identical.
// k2a and all other kernels: R24 verbatim.

#define NB     8
#define NPTS   4096
#define M_TOT  32768
#define CIN    64
#define COUT   128
#define NKP    15
#define NCELL  1728            // 12^3
#define UCAP   400             // union cap (mean ~70)
#define R2EFF  (0.082f * 0.082f)
#define KP_INV 25.0f           // 1 / KP_EXTENT(0.04)
#define NEG_SLOPE 0.2f
#define KCP    960             // kc' = k*64+c, k-major, k=15 dropped
#define WFROW  1920            // wf row stride bytes (960 bf16)
#define SP     40              // S/FT row stride (shorts), 80B

typedef float f32x4_t __attribute__((ext_vector_type(4)));
typedef short bf16x8_t __attribute__((ext_vector_type(8)));

__device__ __forceinline__ unsigned short f2bf(float f) {
  union { float f; unsigned u; } v; v.f = f;
  unsigned r = v.u + 0x7FFF + ((v.u >> 16) & 1);   // RNE
  return (unsigned short)(r >> 16);
}
// half-up rounding: same 0.5 ulp max error as RNE, 2 VALU ops
__device__ __forceinline__ unsigned short f2bf_fast(float f) {
  union { float f; unsigned u; } v; v.f = f;
  return (unsigned short)((v.u + 0x8000u) >> 16);
}
__device__ __forceinline__ int cell_of(float x, float y, float z) {
  int cx = (int)(x * 12.f); cx = cx > 11 ? 11 : cx;
  int cy = (int)(y * 12.f); cy = cy > 11 ? 11 : cy;
  int cz = (int)(z * 12.f); cz = cz > 11 ? 11 : cz;
  return (cz * 12 + cy) * 12 + cx;
}
// async global->LDS, 16B per lane; LDS dest = uniform base + lane*16
__device__ __forceinline__ void gld_lds16(const unsigned short* g, void* l) {
  __builtin_amdgcn_global_load_lds(
      (const __attribute__((address_space(1))) unsigned int*)g,
      (__attribute__((address_space(3))) unsigned int*)l, 16, 0, 0);
}

// ---------------------------------------------------------------------------
// K0a: per-cell histogram
// ---------------------------------------------------------------------------
__global__ __launch_bounds__(256) void k0a_hist(
    const float* __restrict__ xyz, int* __restrict__ cellcnt)
{
  const int pt = blockIdx.x * 256 + threadIdx.x;
  const float x = xyz[pt * 3], y = xyz[pt * 3 + 1], z = xyz[pt * 3 + 2];
  const int b = pt >> 12;
  atomicAdd(&cellcnt[b * NCELL + cell_of(x, y, z)], 1);
}

// ---------------------------------------------------------------------------
// K0b: blocks 0..7 = per-batch exclusive scan; blocks 8..39 = W -> Wt
// Wt[d][k*64+c] bf16, k-major, k=15 dropped.
// ---------------------------------------------------------------------------
__global__ __launch_bounds__(256) void k0b_scan_kW(
    const int* __restrict__ cellcnt, int* __restrict__ cellstart,
    const float* __restrict__ W, unsigned short* __restrict__ Wt)
{
  if (blockIdx.x >= 8) {
    const int idx = (blockIdx.x - 8) * 256 + threadIdx.x;  // 8192
    const int c = idx & 63, d = idx >> 6;                  // d 0..127
    #pragma unroll
    for (int k = 0; k < NKP; k++)
      Wt[(size_t)d * KCP + k * 64 + c] =
          f2bf(W[(size_t)k * (CIN * COUT) + c * COUT + d]);
    return;
  }
  __shared__ int ps[256];
  const int b = blockIdx.x, t = threadIdx.x;
  int local[7], s = 0;
  #pragma unroll
  for (int i = 0; i < 7; i++) {
    const int cid = t * 7 + i;
    const int c = (cid < NCELL) ? cellcnt[b * NCELL + cid] : 0;
    local[i] = c; s += c;
  }
  ps[t] = s; __syncthreads();
  for (int off = 1; off < 256; off <<= 1) {
    int v = (t >= off) ? ps[t - off] : 0;
    __syncthreads();
    ps[t] += v;
    __syncthreads();
  }
  int run = ps[t] - s;
  #pragma unroll
  for (int i = 0; i < 7; i++) {
    const int cid = t * 7 + i;
    if (cid < NCELL) { cellstart[b * 1729 + cid] = run; run += local[i]; }
  }
  if (t == 255) cellstart[b * 1729 + NCELL] = ps[255];
}

// ---------------------------------------------------------------------------
// K0c: counting-sort scatter -> qorder + sorted xyz + sorted bf16 feats
// ---------------------------------------------------------------------------
__global__ __launch_bounds__(256) void k0c_scatter(
    const float* __restrict__ xyz, const float* __restrict__ feats,
    const int* __restrict__ cellstart, int* __restrict__ cellfill,
    int* __restrict__ qorder, float4* __restrict__ xyzs,
    unsigned short* __restrict__ fsorted)
{
  const int pt = blockIdx.x * 256 + threadIdx.x;
  const float x = xyz[pt * 3], y = xyz[pt * 3 + 1], z = xyz[pt * 3 + 2];
  const int b = pt >> 12;
  const int cid = cell_of(x, y, z);
  const int slot = atomicAdd(&cellfill[b * NCELL + cid], 1);
  const int pos = b * NPTS + cellstart[b * 1729 + cid] + slot;
  qorder[pos] = pt;
  xyzs[pos] = make_float4(x, y, z, 0.f);
  const float* src = &feats[(size_t)pt * CIN];
  uint4* dst = (uint4*)&fsorted[(size_t)pos * CIN];
  #pragma unroll
  for (int g = 0; g < 8; g++) {
    float4 a = *(const float4*)(src + g * 8);
    float4 c = *(const float4*)(src + g * 8 + 4);
    union { unsigned short s[8]; uint4 v; } u;
    u.s[0] = f2bf(a.x); u.s[1] = f2bf(a.y); u.s[2] = f2bf(a.z); u.s[3] = f2bf(a.w);
    u.s[4] = f2bf(c.x); u.s[5] = f2bf(c.y); u.s[6] = f2bf(c.z); u.s[7] = f2bf(c.w);
    dst[g] = u.v;
  }
}

// ---------------------------------------------------------------------------
// K2a: search + stage-1, result -> wfg[32768][960] bf16 (coalesced dump)
// ---------------------------------------------------------------------------
__global__ __launch_bounds__(256, 5) void k2a_conv(
    const float4* __restrict__ xyzs, const unsigned short* __restrict__ fsorted,
    const float* __restrict__ kpts, const int* __restrict__ cellstart,
    unsigned short* __restrict__ wfg)
{
  // phase-aliased LDS (32000 B):
  //   [0..6400)       Pu[400] float4
  //   [6400..14592)   cpos[4096] ushort
  //   [6400..26880)   S[128][40] short
  //   [26880..32000)  FT[64][40] short
  //   [0..30720)      wf 16 x 1920 B (XOR-swizzled; writeback+dump)
  __shared__ char smraw[32000] __attribute__((aligned(16)));
  float4*         Pu   = (float4*)smraw;
  unsigned short* cpos = (unsigned short*)(smraw + 6400);
  short (*S)[SP]       = (short(*)[SP])(smraw + 6400);
  short (*FT)[SP]      = (short(*)[SP])(smraw + 26880);

  __shared__ float4 qd[16];
  __shared__ float  kp[NKP][4];   // (-2kx, -2ky, -2kz, |kp|^2)
  __shared__ int    Tsh;
  __shared__ int    ucnt;

  const int tid = threadIdx.x;
  const int w   = tid >> 6;
  const int L   = tid & 63;
  // XCD batch swizzle: XCD x (= bid&7) owns tiles [x*256, x*256+256) ==
  // batch x exactly -> per-XCD gather set (fsorted 512KB + xyzs 64KB) L2-hot.
  const int tile = ((blockIdx.x & 7) << 8) | (blockIdx.x >> 3);
  const int m0  = tile * 16;
  const int b   = blockIdx.x & 7;

  if (tid >= 64 && tid < 64 + NKP) {
    const int k = tid - 64;
    const float kx = kpts[k * 3], ky = kpts[k * 3 + 1], kz = kpts[k * 3 + 2];
    kp[k][0] = -2.f * kx; kp[k][1] = -2.f * ky; kp[k][2] = -2.f * kz;
    kp[k][3] = kx * kx + ky * ky + kz * kz;
  }

  // ---- wave-0 prologue: bbox -> row ranges -> pfx (shfl scan) -> cpos ----
  if (tid < 64) {
    int cxm = 12, cym = 12, czm = 12, cxM = -1, cyM = -1, czM = -1;
    if (tid < 16) {
      const float4 Q = xyzs[m0 + tid];
      qd[tid] = Q;
      int a = (int)(Q.x * 12.f); a = a > 11 ? 11 : a;
      int c = (int)(Q.y * 12.f); c = c > 11 ? 11 : c;
      int d = (int)(Q.z * 12.f); d = d > 11 ? 11 : d;
      cxm = cxM = a; cym = cyM = c; czm = czM = d;
    }
    #pragma unroll
    for (int off = 8; off >= 1; off >>= 1) {
      int v;
      v = __shfl_xor(cxm, off); cxm = v < cxm ? v : cxm;
      v = __shfl_xor(cxM, off); cxM = v > cxM ? v : cxM;
      v = __shfl_xor(cym, off); cym = v < cym ? v : cym;
      v = __shfl_xor(cyM, off); cyM = v > cyM ? v : cyM;
      v = __shfl_xor(czm, off); czm = v < czm ? v : czm;
      v = __shfl_xor(czM, off); czM = v > czM ? v : czM;
    }
    cxm = __shfl(cxm, 0); cxM = __shfl(cxM, 0);
    cym = __shfl(cym, 0); cyM = __shfl(cyM, 0);
    czm = __shfl(czm, 0); czM = __shfl(czM, 0);

    const int x0 = cxm > 0 ? cxm - 1 : 0, x1 = cxM < 11 ? cxM + 1 : 11;
    const int y0 = cym > 0 ? cym - 1 : 0, y1 = cyM < 11 ? cyM + 1 : 11;
    const int z0 = czm > 0 ? czm - 1 : 0, z1 = czM < 11 ? czM + 1 : 11;
    const int yspan = y1 - y0 + 1;
    int nr = yspan * (z1 - z0 + 1);
    nr = nr > 64 ? 64 : nr;

    int rs = 0, len = 0;
    if (tid < nr) {
      const int zz = z0 + tid / yspan, yy = y0 + tid % yspan;
      const int base = b * 1729 + (zz * 12 + yy) * 12;
      rs  = cellstart[base + x0];
      len = cellstart[base + x1 + 1] - rs;
    }
    int incl = len;
    #pragma unroll
    for (int off = 1; off < 64; off <<= 1) {
      const int v = __shfl_up(incl, off);
      if (tid >= off) incl += v;
    }
    const int excl = incl - len;
    for (int i = 0; i < len; i++) cpos[excl + i] = (unsigned short)(rs + i);
    if (tid == 63) Tsh = incl;
    if (tid == 62) ucnt = 0;
  }
  __syncthreads();
  const int T = Tsh;

  // ---- union search: any-hit over 16 queries, branch-free test ----
  for (int tb = 0; tb < T; tb += 256) {
    const int t = tb + tid;
    if (t < T) {
      const int pos = (int)cpos[t];
      const float4 P = xyzs[b * NPTS + pos];
      float best = 1e9f;
      #pragma unroll
      for (int i = 0; i < 16; i++) {
        const float4 Q = qd[i];
        const float dx = P.x - Q.x, dy = P.y - Q.y, dz = P.z - Q.z;
        const float d2 = dx * dx + dy * dy + dz * dz;
        best = d2 < best ? d2 : best;
      }
      if (best <= R2EFF) {
        const int slot = atomicAdd(&ucnt, 1);
        if (slot < UCAP)
          Pu[slot] = make_float4(P.x, P.y, P.z, __int_as_float(pos));
      }
    }
  }
  __syncthreads();
  int U = ucnt; U = U > UCAP ? UCAP : U;

  // ---- stage-1: chunked MFMA over the union, two 8-query half-passes ----
  const int ln = L & 15;
  const int kh = L >> 4;
  const int qh = tid >> 5;      // 0..7 local query of this half
  const int nn = tid & 31;      // chunk column

  f32x4_t acc[16];
  #pragma unroll
  for (int mt = 0; mt < 16; mt++) acc[mt] = (f32x4_t){0.f, 0.f, 0.f, 0.f};

  for (int ub = 0; ub < U; ub += 32) {
    // FT[c][i]: sorted bf16 rows (L2-hot, spatially local)
    {
      const int c  = tid & 63;
      const int i0 = tid >> 6;
      #pragma unroll
      for (int ii = 0; ii < 8; ii++) {
        const int i = ii * 4 + i0;
        const int u = ub + i;
        short v = 0;
        if (u < U) {
          const int pos = __float_as_int(Pu[u].w);
          v = (short)fsorted[(size_t)(b * NPTS + pos) * CIN + c];
        }
        FT[c][i] = v;
      }
    }

    bf16x8_t bb;   // FT fragment, reused by both halves
    #pragma unroll
    for (int half = 0; half < 2; half++) {
      // S fill: one (q, n) pair per thread for queries half*8 .. half*8+7
      {
        const int u = ub + nn;
        if (u < U) {
          const float4 P = Pu[u];
          const float4 Q = qd[half * 8 + qh];
          const float rx = P.x - Q.x, ry = P.y - Q.y, rz = P.z - Q.z;
          const float rr = rx * rx + ry * ry + rz * rz;
          #pragma unroll
          for (int k = 0; k < NKP; k++) {
            float d2 = fmaf(kp[k][0], rx,
                       fmaf(kp[k][1], ry,
                       fmaf(kp[k][2], rz, rr + kp[k][3])));
            d2 = fmaxf(d2, 0.f);
            const float wv =
                fmaxf(fmaf(-KP_INV, __builtin_amdgcn_sqrtf(d2), 1.f), 0.f);
            S[qh * 16 + k][nn] = (short)f2bf_fast(wv);
          }
          S[qh * 16 + 15][nn] = 0;
        } else {
          #pragma unroll
          for (int k = 0; k < 16; k++) S[qh * 16 + k][nn] = 0;
        }
      }
      __syncthreads();
      if (half == 0) bb = *(const bf16x8_t*)&FT[w * 16 + ln][kh * 8];
      #pragma unroll
      for (int mt = 0; mt < 8; mt++) {
        bf16x8_t aa = *(const bf16x8_t*)&S[mt * 16 + ln][kh * 8];
        acc[half * 8 + mt] =
            __builtin_amdgcn_mfma_f32_16x16x32_bf16(aa, bb, acc[half * 8 + mt],
                                                    0, 0, 0);
      }
      __syncthreads();
    }
  }

  // ---- writeback: acc -> LDS wf (swizzled; S/FT/Pu dead) ----
  {
    const int c = w * 16 + ln;
    #pragma unroll
    for (int mt = 0; mt < 16; mt++) {
      #pragma unroll
      for (int j = 0; j < 4; j++) {
        const int k = kh * 4 + j;
        if (k < 15) {
          const int byteo = (mt * WFROW + ((k * 64 + c) << 1)) ^ ((mt & 7) << 4);
          *(unsigned short*)(smraw + byteo) = f2bf_fast(acc[mt][j]);
        }
      }
    }
  }
  __syncthreads();

  // ---- dump: LDS wf -> wfg linear, coalesced uint4 (30720 B/block) ----
  for (int i = tid; i < 16 * 120; i += 256) {
    const int r  = i / 120;
    const int ch = i - r * 120;
    const uint4 v =
        *(const uint4*)(smraw + ((r * WFROW + ch * 16) ^ ((r & 7) << 4)));
    *(uint4*)(wfg + (size_t)(m0 + r) * KCP + ch * 8) = v;
  }
}

// ---------------------------------------------------------------------------
// K2b: tiled GEMM out[32768][128] = wfg[32768][960] @ Wt[128][960]^T
// 256 blocks x 128x128 tile, BK=64, 4 waves 2x2 (64x64 each), glds staging,
// double-buffered with COUNTED vmcnt(8): the in-flight prefetch is never
// drained (was vmcnt(0) via __syncthreads = ~600-900cy stall x 15 steps).
// Raw s_barrier x2 per step: #1 after vmcnt(8) = buffer ready on all waves;
// #2 after compute = all waves done reading before next-iter overwrite.
// kc accumulation order unchanged -> out bitwise identical to R20/R24.
// ---------------------------------------------------------------------------
__global__ __launch_bounds__(256, 2) void k2b_gemm(
    const unsigned short* __restrict__ wfg,
    const unsigned short* __restrict__ Wt,
    const int* __restrict__ qorder, float* __restrict__ out,
    float* __restrict__ psum, float* __restrict__ psumsq)
{
  __shared__ char smA[2][16384] __attribute__((aligned(16)));
  __shared__ char smB[2][16384] __attribute__((aligned(16)));
  __shared__ int  qm[128];

  const int tid = threadIdx.x;
  const int w   = tid >> 6;
  const int L   = tid & 63;
  const int m0  = blockIdx.x * 128;

  if (tid < 128) qm[tid] = qorder[m0 + tid];

  const int c16 = L & 7;

#define STAGE_TILES(buf, ks)                                                 \
  {                                                                          \
    _Pragma("unroll")                                                        \
    for (int i = 0; i < 4; i++) {                                            \
      const int row = (w * 4 + i) * 8 + (L >> 3);                            \
      const int sc  = (c16 ^ (row & 7)) << 3;   /* shorts */                 \
      gld_lds16(wfg + (size_t)(m0 + row) * KCP + (ks) * 64 + sc,             \
                (char*)smA[buf] + (w * 4 + i) * 1024);                       \
      gld_lds16(Wt + (size_t)row * KCP + (ks) * 64 + sc,                     \
                (char*)smB[buf] + (w * 4 + i) * 1024);                       \
    }                                                                        \
  }

  // prologue: stage ks=0 into buf 0 (no drain; first wait is counted)
  STAGE_TILES(0, 0)

  const int wr = w >> 1, wc = w & 1;
  const int ln = L & 15, kh = L >> 4;

  f32x4_t acc[4][4];
  #pragma unroll
  for (int mt = 0; mt < 4; mt++)
    #pragma unroll
    for (int nt = 0; nt < 4; nt++)
      acc[mt][nt] = (f32x4_t){0.f, 0.f, 0.f, 0.f};

  #pragma unroll
  for (int ks = 0; ks < 15; ks++) {
    const int cur = ks & 1;
    // issue next stage into the other buffer (8 glds stay in flight
    // across the barrier -- never drained until one iteration later)
    if (ks < 14) STAGE_TILES(cur ^ 1, ks + 1)

    // wait ONLY for buf[cur]'s 8 loads (the 8 just issued may remain
    // outstanding). vmcnt retires in issue order; "memory" clobber keeps
    // the dependent ds_reads below this point.
    if (ks < 14) asm volatile("s_waitcnt vmcnt(8)" ::: "memory");
    else         asm volatile("s_waitcnt vmcnt(0)" ::: "memory");
    __builtin_amdgcn_s_barrier();   // all waves' buf[cur] loads complete

    const char* cA = smA[cur];
    const char* cB = smB[cur];
    #pragma unroll
    for (int ks2 = 0; ks2 < 2; ks2++) {
      bf16x8_t a[4], bfr[4];
      #pragma unroll
      for (int mt = 0; mt < 4; mt++) {
        const int row  = wr * 64 + mt * 16 + ln;
        const int phys = ((ks2 * 4 + kh) ^ (row & 7)) << 4;
        a[mt] = *(const bf16x8_t*)(cA + row * 128 + phys);
      }
      #pragma unroll
      for (int nt = 0; nt < 4; nt++) {
        const int row  = wc * 64 + nt * 16 + ln;
        const int phys = ((ks2 * 4 + kh) ^ (row & 7)) << 4;
        bfr[nt] = *(const bf16x8_t*)(cB + row * 128 + phys);
      }
      #pragma unroll
      for (int mt = 0; mt < 4; mt++)
        #pragma unroll
        for (int nt = 0; nt < 4; nt++)
          acc[mt][nt] = __builtin_amdgcn_mfma_f32_16x16x32_bf16(
              a[mt], bfr[nt], acc[mt][nt], 0, 0, 0);
    }
    // all waves done READING buf[cur] before iter ks+1 overwrites it
    asm volatile("s_waitcnt lgkmcnt(0)" ::: "memory");
    __builtin_amdgcn_s_barrier();
  }
#undef STAGE_TILES

  // ---- BN partials: column sums over this block's 128 rows ----
  #pragma unroll
  for (int nt = 0; nt < 4; nt++) {
    float s = 0.f, q = 0.f;
    #pragma unroll
    for (int mt = 0; mt < 4; mt++)
      #pragma unroll
      for (int j = 0; j < 4; j++) {
        const float v = acc[mt][nt][j];
        s += v; q += v * v;
      }
    s += __shfl_xor(s, 16); s += __shfl_xor(s, 32);
    q += __shfl_xor(q, 16); q += __shfl_xor(q, 32);
    if (kh == 0) {
      atomicAdd(&psum[wc * 64 + nt * 16 + ln], s);
      atomicAdd(&psumsq[wc * 64 + nt * 16 + ln], q);
    }
  }

  // ---- C scatter via qm (C/D: col=lane&15, row=(lane>>4)*4+reg) ----
  #pragma unroll
  for (int mt = 0; mt < 4; mt++) {
    #pragma unroll
    for (int j = 0; j < 4; j++) {
      const int r = wr * 64 + mt * 16 + kh * 4 + j;
      const size_t ob = (size_t)qm[r] * COUT + wc * 64 + ln;
      #pragma unroll
      for (int nt = 0; nt < 4; nt++)
        out[ob + nt * 16] = acc[mt][nt][j];
    }
  }
}

// ---------------------------------------------------------------------------
// K2_old: R14 fused kernel (fallback when workspace too small for wfg)
// ---------------------------------------------------------------------------
__global__ __launch_bounds__(256, 5) void k2_old(
    const float4* __restrict__ xyzs, const unsigned short* __restrict__ fsorted,
    const float* __restrict__ kpts, const int* __restrict__ cellstart,
    const int* __restrict__ qorder, const unsigned short* __restrict__ Wt,
    float* __restrict__ out, float* __restrict__ psum,
    float* __restrict__ psumsq)
{
  __shared__ char smraw[32000] __attribute__((aligned(16)));
  float4*         Pu   = (float4*)smraw;
  unsigned short* cpos = (unsigned short*)(smraw + 6400);
  short (*S)[SP]       = (short(*)[SP])(smraw + 6400);
  short (*FT)[SP]      = (short(*)[SP])(smraw + 26880);

  __shared__ float4 qd[16];
  __shared__ int    qm[16];
  __shared__ float  kp[NKP][4];
  __shared__ int    Tsh;
  __shared__ int    ucnt;

  const int tid = threadIdx.x;
  const int w   = tid >> 6;
  const int L   = tid & 63;
  const int m0  = blockIdx.x * 16;
  const int b   = m0 >> 12;

  if (tid >= 64 && tid < 64 + NKP) {
    const int k = tid - 64;
    const float kx = kpts[k * 3], ky = kpts[k * 3 + 1], kz = kpts[k * 3 + 2];
    kp[k][0] = -2.f * kx; kp[k][1] = -2.f * ky; kp[k][2] = -2.f * kz;
    kp[k][3] = kx * kx + ky * ky + kz * kz;
  }

  if (tid < 64) {
    int cxm = 12, cym = 12, czm = 12, cxM = -1, cyM = -1, czM = -1;
    if (tid < 16) {
      const float4 Q = xyzs[m0 + tid];
      qd[tid] = Q;
      qm[tid] = qorder[m0 + tid];
      int a = (int)(Q.x * 12.f); a = a > 11 ? 11 : a;
      int c = (int)(Q.y * 12.f); c = c > 11 ? 11 : c;
      int d = (int)(Q.z * 12.f); d = d > 11 ? 11 : d;
      cxm = cxM = a; cym = cyM = c; czm = czM = d;
    }
    #pragma unroll
    for (int off = 8; off >= 1; off >>= 1) {
      int v;
      v = __shfl_xor(cxm, off); cxm = v < cxm ? v : cxm;
      v = __shfl_xor(cxM, off); cxM = v > cxM ? v : cxM;
      v = __shfl_xor(cym, off); cym = v < cym ? v : cym;
      v = __shfl_xor(cyM, off); cyM = v > cyM ? v : cyM;
      v = __shfl_xor(czm, off); czm = v < czm ? v : czm;
      v = __shfl_xor(czM, off); czM = v > czM ? v : czM;
    }
    cxm = __shfl(cxm, 0); cxM = __shfl(cxM, 0);
    cym = __shfl(cym, 0); cyM = __shfl(cyM, 0);
    czm = __shfl(czm, 0); czM = __shfl(czM, 0);

    const int x0 = cxm > 0 ? cxm - 1 : 0, x1 = cxM < 11 ? cxM + 1 : 11;
    const int y0 = cym > 0 ? cym - 1 : 0, y1 = cyM < 11 ? cyM + 1 : 11;
    const int z0 = czm > 0 ? czm - 1 : 0, z1 = czM < 11 ? czM + 1 : 11;
    const int yspan = y1 - y0 + 1;
    int nr = yspan * (z1 - z0 + 1);
    nr = nr > 64 ? 64 : nr;

    int rs = 0, len = 0;
    if (tid < nr) {
      const int zz = z0 + tid / yspan, yy = y0 + tid % yspan;
      const int base = b * 1729 + (zz * 12 + yy) * 12;
      rs  = cellstart[base + x0];
      len = cellstart[base + x1 + 1] - rs;
    }
    int incl = len;
    #pragma unroll
    for (int off = 1; off < 64; off <<= 1) {
      const int v = __shfl_up(incl, off);
      if (tid >= off) incl += v;
    }
    const int excl = incl - len;
    for (int i = 0; i < len; i++) cpos[excl + i] = (unsigned short)(rs + i);
    if (tid == 63) Tsh = incl;
    if (tid == 62) ucnt = 0;
  }
  __syncthreads();
  const int T = Tsh;

  for (int tb = 0; tb < T; tb += 256) {
    const int t = tb + tid;
    if (t < T) {
      const int pos = (int)cpos[t];
      const float4 P = xyzs[b * NPTS + pos];
      float best = 1e9f;
      #pragma unroll
      for (int i = 0; i < 16; i++) {
        const float4 Q = qd[i];
        const float dx = P.x - Q.x, dy = P.y - Q.y, dz = P.z - Q.z;
        const float d2 = dx * dx + dy * dy + dz * dz;
        best = d2 < best ? d2 : best;
      }
      if (best <= R2EFF) {
        const int slot = atomicAdd(&ucnt, 1);
        if (slot < UCAP)
          Pu[slot] = make_float4(P.x, P.y, P.z, __int_as_float(pos));
      }
    }
  }
  __syncthreads();
  int U = ucnt; U = U > UCAP ? UCAP : U;

  const int ln = L & 15;
  const int kh = L >> 4;
  const int qh = tid >> 5;
  const int nn = tid & 31;

  f32x4_t acc[16];
  #pragma unroll
  for (int mt = 0; mt < 16; mt++) acc[mt] = (f32x4_t){0.f, 0.f, 0.f, 0.f};

  for (int ub = 0; ub < U; ub += 32) {
    {
      const int c  = tid & 63;
      const int i0 = tid >> 6;
      #pragma unroll
      for (int ii = 0; ii < 8; ii++) {
        const int i = ii * 4 + i0;
        const int u = ub + i;
        short v = 0;
        if (u < U) {
          const int pos = __float_as_int(Pu[u].w);
          v = (short)fsorted[(size_t)(b * NPTS + pos) * CIN + c];
        }
        FT[c][i] = v;
      }
    }
    bf16x8_t bb;
    #pragma unroll
    for (int half = 0; half < 2; half++) {
      {
        const int u = ub + nn;
        if (u < U) {
          const float4 P = Pu[u];
          const float4 Q = qd[half * 8 + qh];
          const float rx = P.x - Q.x, ry = P.y - Q.y, rz = P.z - Q.z;
          const float rr = rx * rx + ry * ry + rz * rz;
          #pragma unroll
          for (int k = 0; k < NKP; k++) {
            float d2 = fmaf(kp[k][0], rx,
                       fmaf(kp[k][1], ry,
                       fmaf(kp[k][2], rz, rr + kp[k][3])));
            d2 = fmaxf(d2, 0.f);
            const float wv =
                fmaxf(fmaf(-KP_INV, __builtin_amdgcn_sqrtf(d2), 1.f), 0.f);
            S[qh * 16 + k][nn] = (short)f2bf_fast(wv);
          }
          S[qh * 16 + 15][nn] = 0;
        } else {
          #pragma unroll
          for (int k = 0; k < 16; k++) S[qh * 16 + k][nn] = 0;
        }
      }
      __syncthreads();
      if (half == 0) bb = *(const bf16x8_t*)&FT[w * 16 + ln][kh * 8];
      #pragma unroll
      for (int mt = 0; mt < 8; mt++) {
        bf16x8_t aa = *(const bf16x8_t*)&S[mt * 16 + ln][kh * 8];
        acc[half * 8 + mt] =
            __builtin_amdgcn_mfma_f32_16x16x32_bf16(aa, bb, acc[half * 8 + mt],
                                                    0, 0, 0);
      }
      __syncthreads();
    }
  }

  {
    const int c = w * 16 + ln;
    #pragma unroll
    for (int mt = 0; mt < 16; mt++) {
      #pragma unroll
      for (int j = 0; j < 4; j++) {
        const int k = kh * 4 + j;
        if (k < 15) {
          const int byteo = (mt * WFROW + ((k * 64 + c) << 1)) ^ ((mt & 7) << 4);
          *(unsigned short*)(smraw + byteo) = f2bf_fast(acc[mt][j]);
        }
      }
    }
  }
  __syncthreads();

  const int colbase = w * 32;
  f32x4_t acc2[2];
  acc2[0] = (f32x4_t){0.f, 0.f, 0.f, 0.f};
  acc2[1] = (f32x4_t){0.f, 0.f, 0.f, 0.f};

  const unsigned short* Bp0 = &Wt[(size_t)(colbase + ln) * KCP + kh * 8];
  const unsigned short* Bp1 = Bp0 + 16 * KCP;
  const char* wfb = (const char*)smraw + ln * WFROW;
  const int   sw  = (ln & 7) << 4;

  #pragma unroll 6
  for (int kk = 0; kk < 30; kk++) {
    const int ko  = kk * 32;
    const int inr = (kh * 16 + kk * 64) ^ sw;
    bf16x8_t b0 = *(const bf16x8_t*)(Bp0 + ko);
    bf16x8_t b1 = *(const bf16x8_t*)(Bp1 + ko);
    bf16x8_t a0 = *(const bf16x8_t*)(wfb + inr);
    acc2[0] = __builtin_amdgcn_mfma_f32_16x16x32_bf16(a0, b0, acc2[0], 0, 0, 0);
    acc2[1] = __builtin_amdgcn_mfma_f32_16x16x32_bf16(a0, b1, acc2[1], 0, 0, 0);
  }

  float s0 = 0.f, q0 = 0.f, s1 = 0.f, q1 = 0.f;
  #pragma unroll
  for (int j = 0; j < 4; j++) {
    s0 += acc2[0][j]; q0 += acc2[0][j] * acc2[0][j];
    s1 += acc2[1][j]; q1 += acc2[1][j] * acc2[1][j];
  }
  s0 += __shfl_xor(s0, 16); s0 += __shfl_xor(s0, 32);
  q0 += __shfl_xor(q0, 16); q0 += __shfl_xor(q0, 32);
  s1 += __shfl_xor(s1, 16); s1 += __shfl_xor(s1, 32);
  q1 += __shfl_xor(q1, 16); q1 += __shfl_xor(q1, 32);
  if (kh == 0) {
    atomicAdd(&psum[colbase + ln], s0);
    atomicAdd(&psumsq[colbase + ln], q0);
    atomicAdd(&psum[colbase + 16 + ln], s1);
    atomicAdd(&psumsq[colbase + 16 + ln], q1);
  }

  #pragma unroll
  for (int c = 0; c < 2; c++) {
    #pragma unroll
    for (int j = 0; j < 4; j++) {
      const int row = kh * 4 + j;
      out[(size_t)qm[row] * COUT + colbase + c * 16 + ln] = acc2[c][j];
    }
  }
}

// ---------------------------------------------------------------------------
// K4: BN finalize (per-block, from psum) + normalize + LeakyReLU
// ---------------------------------------------------------------------------
__global__ __launch_bounds__(256) void k4_norm(
    float* __restrict__ out, const float* __restrict__ psum,
    const float* __restrict__ psumsq, const float* __restrict__ gamma,
    const float* __restrict__ beta)
{
  __shared__ float a_s[128], b_s[128];
  if (threadIdx.x < 128) {
    const int d = threadIdx.x;
    double mu  = (double)psum[d] / (double)M_TOT;
    double var = (double)psumsq[d] / (double)M_TOT - mu * mu;  // biased
    float rstd = (float)(1.0 / sqrt(var + 1e-5));
    float a = rstd * gamma[d];
    a_s[d] = a;
    b_s[d] = beta[d] - (float)mu * a;
  }
  __syncthreads();
  const int idx = blockIdx.x * 256 + threadIdx.x;   // float4 index
  float4 v = ((const float4*)out)[idx];
  const int d0 = (idx * 4) & 127;
  float y0 = v.x * a_s[d0 + 0] + b_s[d0 + 0];
  float y1 = v.y * a_s[d0 + 1] + b_s[d0 + 1];
  float y2 = v.z * a_s[d0 + 2] + b_s[d0 + 2];
  float y3 = v.w * a_s[d0 + 3] + b_s[d0 + 3];
  v.x = y0 >= 0.f ? y0 : NEG_SLOPE * y0;
  v.y = y1 >= 0.f ? y1 : NEG_SLOPE * y1;
  v.z = y2 >= 0.f ? y2 : NEG_SLOPE * y2;
  v.w = y3 >= 0.f ? y3 : NEG_SLOPE * y3;
  ((float4*)out)[idx] = v;
}

// ---------------------------------------------------------------------------
extern "C" void kernel_launch(void* const* d_in, const int* in_sizes, int n_in,
                              void* d_out, int out_size, void* d_ws,
                              size_t ws_size, hipStream_t stream)
{
  const float* xyz   = (const float*)d_in[0];
  const float* feats = (const float*)d_in[1];
  const float* kpts  = (const float*)d_in[2];
  const float* W     = (const float*)d_in[3];
  const float* gamma = (const float*)d_in[4];
  const float* beta  = (const float*)d_in[5];
  float* out = (float*)d_out;

  char* ws = (char*)d_ws;
  int*            cellcnt   = (int*)(ws + 0);           //  55296 B ─┐
  int*            cellfill  = (int*)(ws + 55296);       //  55296 B  │ zeroed
  float*          psum      = (float*)(ws + 110592);    //    512 B  │
  float*          psumsq    = (float*)(ws + 111104);    //    512 B ─┘
  int*            cellstart = (int*)(ws + 111616);      //  55424 B
  int*            qorder    = (int*)(ws + 167040);      // 131072 B
  float4*         xyzs      = (float4*)(ws + 298112);   // 524288 B
  unsigned short* fsorted   = (unsigned short*)(ws + 822400);   // 4194304 B
  unsigned short* Wtbuf     = (unsigned short*)(ws + 5016704);  // 245760 B
  unsigned short* wfg       = (unsigned short*)(ws + 5262464);  // 62914560 B

  const size_t NEED = 5262464ull + 62914560ull;   // 68,177,024 B

  hipMemsetAsync(ws, 0, 111616, stream);

  if (ws_size >= NEED) {
    k0a_hist    <<< 128, 256, 0, stream>>>(xyz, cellcnt);
    k0b_scan_kW <<<  40, 256, 0, stream>>>(cellcnt, cellstart, W, Wtbuf);
    k0c_scatter <<< 128, 256, 0, stream>>>(xyz, feats, cellstart, cellfill,
                                           qorder, xyzs, fsorted);
    k2a_conv    <<<2048, 256, 0, stream>>>(xyzs, fsorted, kpts, cellstart,
                                           wfg);
    k2b_gemm    <<< 256, 256, 0, stream>>>(wfg, Wtbuf, qorder, out,
                                           psum, psumsq);
    k4_norm     <<<(out_size / 4) / 256, 256, 0, stream>>>(out, psum, psumsq,
                                                           gamma, beta);
  } else {
    k0a_hist    <<< 128, 256, 0, stream>>>(xyz, cellcnt);
    k0b_scan_kW <<<  40, 256, 0, stream>>>(cellcnt, cellstart, W, Wtbuf);
    k0c_scatter <<< 128, 256, 0, stream>>>(xyz, feats, cellstart, cellfill,
                                           qorder, xyzs, fsorted);
    k2_old      <<<2048, 256, 0, stream>>>(xyzs, fsorted, kpts, cellstart,
                                           qorder, Wtbuf, out, psum, psumsq);
    k4_norm     <<<(out_size / 4) / 256, 256, 0, stream>>>(out, psum, psumsq,
                                                           gamma, beta);
  }
}